// Round 11
// baseline (1281.452 us; speedup 1.0000x reference)
//
#include <hip/hip_runtime.h>
#include <cstdint>

#define DEVI __device__ __forceinline__

typedef short short8 __attribute__((ext_vector_type(8)));
typedef float f32x4 __attribute__((ext_vector_type(4)));
typedef unsigned short u16;
typedef u16 u16x4 __attribute__((ext_vector_type(4)));

static constexpr int Bz = 8, Ss = 1024, Dd = 1024, Hh = 16, HD = 64, DFF = 4096, Ee = 16;
static constexpr int Tt = Bz * Ss;           // 8192 tokens
static constexpr int Cap = (2 * Tt) / Ee;    // 1024 capacity
static constexpr int D3 = 3 * Dd;            // 3072
static constexpr float EPSc = 1.1920929e-07f;
static constexpr size_t PT = (size_t)Tt * Dd;   // plane elements (token-major)

DEVI u16 f2b(float f) {
    union { float f; uint32_t u; } v; v.f = f;
    return (u16)((v.u + 0x7FFFu + ((v.u >> 16) & 1u)) >> 16);
}
DEVI float b2f(u16 h) {
    union { uint32_t u; float f; } v; v.u = ((uint32_t)h) << 16; return v.f;
}
DEVI f32x4 zf4() { f32x4 v; v[0] = 0.f; v[1] = 0.f; v[2] = 0.f; v[3] = 0.f; return v; }

// async global->LDS, 16B per lane. LDS dest must be wave-uniform base + lane*16B.
DEVI void gl16(const u16* g, u16* l) {
    __builtin_amdgcn_global_load_lds(
        (const __attribute__((address_space(1))) void*)g,
        (__attribute__((address_space(3))) void*)l, 16, 0, 0);
}

// swizzled u16 index for [R][64] bf16 tiles (128B rows): byte ^= (row&7)<<4
DEVI int swzb(int row, int col) {
    int byte = (row * 64 + col) * 2;
    byte ^= (row & 7) << 4;
    return byte >> 1;
}

// ---------------------------------------------------------------------------
// split fp32 -> 3 bf16 planes (hi/mid/lo), plane stride = n. n % 1024 == 0.
// ---------------------------------------------------------------------------
__global__ __launch_bounds__(256)
void split3_kernel(const float* __restrict__ in, u16* __restrict__ out, long long n) {
    const long long i = ((long long)blockIdx.x * 256 + threadIdx.x) * 4;
    if (i >= n) return;
    const float4 v = *(const float4*)(in + i);
    const float f[4] = {v.x, v.y, v.z, v.w};
    u16x4 ph, pm, pl;
#pragma unroll
    for (int c = 0; c < 4; ++c) {
        const u16 hi = f2b(f[c]);
        const float r1 = f[c] - b2f(hi);     // exact
        const u16 mi = f2b(r1);
        const float r2 = r1 - b2f(mi);       // exact
        const u16 lo = f2b(r2);
        ph[c] = hi; pm[c] = mi; pl[c] = lo;
    }
    *(u16x4*)(out + i) = ph;
    *(u16x4*)(out + n + i) = pm;
    *(u16x4*)(out + 2 * n + i) = pl;
}

// ---------------------------------------------------------------------------
// transpose + convert, vectorized: in [Z][R][Cc] f32 -> out [Z][Cc][R] bf16
// ---------------------------------------------------------------------------
__global__ __launch_bounds__(256)
void tconv64_kernel(const float* __restrict__ in, u16* __restrict__ out, int R, int Cc) {
    __shared__ u16 tile[64][68];
    const int z = blockIdx.z;
    const int r0 = blockIdx.y * 64, c0 = blockIdx.x * 64;
    const int tr = threadIdx.x >> 4;          // 0..15
    const int tc4 = (threadIdx.x & 15) * 4;   // 0..60
    const float* ip = in + (size_t)z * R * Cc;
#pragma unroll
    for (int i = 0; i < 4; ++i) {
        const int row = tr + i * 16;
        const float4 v = *(const float4*)(ip + (size_t)(r0 + row) * Cc + c0 + tc4);
        u16x4 w;
        w[0] = f2b(v.x); w[1] = f2b(v.y); w[2] = f2b(v.z); w[3] = f2b(v.w);
        *(u16x4*)(&tile[row][tc4]) = w;
    }
    __syncthreads();
    u16* op = out + (size_t)z * R * Cc;
#pragma unroll
    for (int i = 0; i < 4; ++i) {
        const int orow = tr + i * 16;
        u16x4 w;
#pragma unroll
        for (int j = 0; j < 4; ++j) w[j] = tile[tc4 + j][orow];
        *(u16x4*)(op + (size_t)(c0 + orow) * R + r0 + tc4) = w;
    }
}

// ---------------------------------------------------------------------------
// V-plane transpose: vh/vl [Tt][Dd] (per bh: [s][64]) -> vth/vtl [bh][64][Ss]
// ---------------------------------------------------------------------------
__global__ __launch_bounds__(256)
void vtrans_kernel(const u16* __restrict__ vh, const u16* __restrict__ vl,
                   u16* __restrict__ vth, u16* __restrict__ vtl) {
    __shared__ u16 th[32][33], tl[32][33];
    const int bh = blockIdx.z, d0 = blockIdx.y * 32, s0 = blockIdx.x * 32;
    const int bb = bh >> 4, hh = bh & 15;
    const int tr = threadIdx.x >> 5, tc = threadIdx.x & 31;
#pragma unroll
    for (int i = 0; i < 4; ++i) {
        const size_t src = (size_t)(bb * Ss + s0 + tr + i * 8) * Dd + hh * HD + d0 + tc;
        th[tr + i * 8][tc] = vh[src];
        tl[tr + i * 8][tc] = vl[src];
    }
    __syncthreads();
#pragma unroll
    for (int i = 0; i < 4; ++i) {
        const size_t dst = ((size_t)bh * HD + d0 + tr + i * 8) * Ss + s0 + tc;
        vth[dst] = th[tc][tr + i * 8];
        vtl[dst] = tl[tc][tr + i * 8];
    }
}

// ---------------------------------------------------------------------------
// 3-split MFMA BT-GEMM (routing path) — PROVEN round-6 structure restored:
// 128x128 tile, BK=32, 4 waves, single-buffer, global_load_lds, 2 barriers.
// MODE: 2 f32 out, 3 QKV split-plane out. 6 products, bit-stable chain.
// ---------------------------------------------------------------------------
template <int SPLITS, int MODE>
__global__ __launch_bounds__(256)
void gemm_gl(const u16* __restrict__ A, const u16* __restrict__ Bt, void* __restrict__ Cout,
             const float* __restrict__ bias, int M, int N, int K,
             size_t psA, size_t psB,
             u16* __restrict__ qh, u16* __restrict__ ql,
             u16* __restrict__ kh, u16* __restrict__ kl,
             u16* __restrict__ vh, u16* __restrict__ vl) {
    __shared__ u16 As[SPLITS * 128 * 32];
    __shared__ u16 Bs[SPLITS * 128 * 32];
    const int tid = threadIdx.x;
    const int lane = tid & 63, wid = tid >> 6;
    const int wm = wid >> 1, wn = wid & 1;
    const int m0 = blockIdx.y * 128, n0 = blockIdx.x * 128;
    const int lr = lane & 15, lg = lane >> 4;
    const int lrow = lane >> 2;          // 0..15
    const int lcol = (lane & 3) * 8;     // 0,8,16,24

    f32x4 acc[4][4];
#pragma unroll
    for (int i = 0; i < 4; ++i)
#pragma unroll
        for (int j = 0; j < 4; ++j) acc[i][j] = zf4();

    for (int kt = 0; kt < K; kt += 32) {
#pragma unroll
        for (int p = 0; p < SPLITS; ++p) {
#pragma unroll
            for (int c = 0; c < 2; ++c) {
                const int r0 = wid * 32 + c * 16;
                gl16(A + p * psA + (size_t)(m0 + r0 + lrow) * K + kt + lcol,
                     As + p * 4096 + r0 * 32 + lane * 8);
                gl16(Bt + p * psB + (size_t)(n0 + r0 + lrow) * K + kt + lcol,
                     Bs + p * 4096 + r0 * 32 + lane * 8);
            }
        }
        __syncthreads();

        short8 af[SPLITS][4];
#pragma unroll
        for (int p = 0; p < SPLITS; ++p)
#pragma unroll
            for (int i = 0; i < 4; ++i)
                af[p][i] = *(const short8*)(As + p * 4096 + (wm * 64 + i * 16 + lr) * 32 + lg * 8);

#pragma unroll
        for (int bp = 0; bp < SPLITS; ++bp) {
            short8 bf[4];
#pragma unroll
            for (int j = 0; j < 4; ++j)
                bf[j] = *(const short8*)(Bs + bp * 4096 + (wn * 64 + j * 16 + lr) * 32 + lg * 8);
#pragma unroll
            for (int ap = 0; ap + bp < SPLITS; ++ap)
#pragma unroll
                for (int i = 0; i < 4; ++i)
#pragma unroll
                    for (int j = 0; j < 4; ++j)
                        acc[i][j] = __builtin_amdgcn_mfma_f32_16x16x32_bf16(af[ap][i], bf[j], acc[i][j], 0, 0, 0);
        }
        __syncthreads();
    }

    const int r4 = lg * 4;
    const int region = n0 >> 10;   // MODE 3: 0=Q,1=K,2=V (uniform per block)
#pragma unroll
    for (int j = 0; j < 4; ++j) {
        const int col = n0 + wn * 64 + j * 16 + lr;
        const float bv = bias[col];
#pragma unroll
        for (int i = 0; i < 4; ++i) {
#pragma unroll
            for (int r = 0; r < 4; ++r) {
                const int rowg = m0 + wm * 64 + i * 16 + r4 + r;
                float v = acc[i][j][r] + bv;
                if (MODE == 2) {
                    ((float*)Cout)[(size_t)rowg * N + col] = v;
                } else {
                    const size_t off = (size_t)rowg * Dd + (col & 1023);
                    if (region == 0) {
                        const float fs = v * 0.125f;
                        const u16 h = f2b(fs);
                        qh[off] = h; ql[off] = f2b(fs - b2f(h));
                    } else if (region == 1) {
                        const u16 h = f2b(v);
                        kh[off] = h; kl[off] = f2b(v - b2f(h));
                    } else {
                        const u16 h = f2b(v);
                        vh[off] = h; vl[off] = f2b(v - b2f(h));
                    }
                }
            }
        }
    }
}

// ---------------------------------------------------------------------------
// Expert GEMM, 256x256 tile, BK=64, 8 waves, double-buffered LDS,
// counted vmcnt(8) + XOR bank swizzle (validated rounds 7-10).
// ---------------------------------------------------------------------------
template <int RELU>
__global__ __launch_bounds__(512)
void gemm_x2(const u16* __restrict__ A, const u16* __restrict__ Bt, u16* __restrict__ Cout,
             const float* __restrict__ bias, int M, int N, int K,
             size_t sA, size_t sB, size_t sC, int sBias) {
    __shared__ u16 lds[2][2][256 * 64];   // 128 KiB
    const int tid = threadIdx.x, lane = tid & 63, wid = tid >> 6;
    const int wm = wid >> 2, wn = wid & 3;
    const int lr = lane & 15, lg = lane >> 4;
    const int m0 = blockIdx.y * 256, n0 = blockIdx.x * 256;
    const int e = blockIdx.z;
    const u16* Ab = A + (size_t)e * sA;
    const u16* Bb = Bt + (size_t)e * sB;

    const int srow = wid * 8 + (lane >> 3);
    const int sscol = (((lane & 7) ^ ((lane >> 3) & 7))) * 8;

    f32x4 acc[8][4];
#pragma unroll
    for (int i = 0; i < 8; ++i)
#pragma unroll
        for (int j = 0; j < 4; ++j) acc[i][j] = zf4();

#define STAGE_X2(b, kt)                                                              \
    {                                                                                \
        _Pragma("unroll")                                                            \
        for (int c = 0; c < 4; ++c)                                                  \
            gl16(Ab + (size_t)(m0 + c * 64 + srow) * K + (kt) + sscol,               \
                 &lds[b][0][(c * 64 + srow) * 64 + (lane & 7) * 8]);                 \
        _Pragma("unroll")                                                            \
        for (int c = 0; c < 4; ++c)                                                  \
            gl16(Bb + (size_t)(n0 + c * 64 + srow) * K + (kt) + sscol,               \
                 &lds[b][1][(c * 64 + srow) * 64 + (lane & 7) * 8]);                 \
    }

#define COMPUTE_X2(b)                                                                \
    {                                                                                \
        _Pragma("unroll")                                                            \
        for (int ks = 0; ks < 2; ++ks) {                                             \
            short8 af[8], bf[4];                                                     \
            _Pragma("unroll")                                                        \
            for (int i = 0; i < 8; ++i)                                              \
                af[i] = *(const short8*)(&lds[b][0][(wm * 128 + i * 16 + lr) * 64 +  \
                                                    (((ks * 4 + lg) ^ (lr & 7)) * 8)]); \
            _Pragma("unroll")                                                        \
            for (int j = 0; j < 4; ++j)                                              \
                bf[j] = *(const short8*)(&lds[b][1][(wn * 64 + j * 16 + lr) * 64 +   \
                                                    (((ks * 4 + lg) ^ (lr & 7)) * 8)]); \
            _Pragma("unroll")                                                        \
            for (int i = 0; i < 8; ++i)                                              \
                _Pragma("unroll")                                                    \
                for (int j = 0; j < 4; ++j)                                          \
                    acc[i][j] = __builtin_amdgcn_mfma_f32_16x16x32_bf16(af[i], bf[j], acc[i][j], 0, 0, 0); \
        }                                                                            \
    }

    const int nt = K >> 6;
    STAGE_X2(0, 0)
    for (int t = 0; t < nt - 1; ++t) {
        const int cur = t & 1;
        STAGE_X2(cur ^ 1, (t + 1) * 64)
        asm volatile("s_waitcnt vmcnt(8)" ::: "memory");
        __builtin_amdgcn_s_barrier();
        COMPUTE_X2(cur)
        asm volatile("s_waitcnt lgkmcnt(0)" ::: "memory");
        __builtin_amdgcn_s_barrier();
    }
    asm volatile("s_waitcnt vmcnt(0)" ::: "memory");
    __builtin_amdgcn_s_barrier();
    COMPUTE_X2((nt - 1) & 1)

#undef STAGE_X2
#undef COMPUTE_X2

    const int r4 = lg * 4;
#pragma unroll
    for (int j = 0; j < 4; ++j) {
        const int col = n0 + wn * 64 + j * 16 + lr;
        const float bv = bias[(size_t)e * sBias + col];
#pragma unroll
        for (int i = 0; i < 8; ++i) {
#pragma unroll
            for (int r = 0; r < 4; ++r) {
                const int rowg = m0 + wm * 128 + i * 16 + r4 + r;
                float v = acc[i][j][r] + bv;
                if (RELU) v = fmaxf(v, 0.f);
                Cout[(size_t)e * sC + (size_t)rowg * N + col] = f2b(v);
            }
        }
    }
}

// ---------------------------------------------------------------------------
// Split-bf16 MFMA flash attention + T14 register prefetch of next K/V tile.
// Values / MFMA order / softmax bit-identical to validated rounds 6-10;
// only the load scheduling changed (prefetch hides HBM under compute).
// ---------------------------------------------------------------------------
__global__ __launch_bounds__(256)
void attn_mfma(const u16* __restrict__ qhp, const u16* __restrict__ qlp,
               const u16* __restrict__ khp, const u16* __restrict__ klp,
               const u16* __restrict__ vthp, const u16* __restrict__ vtlp,
               u16* __restrict__ os) {
    __shared__ u16 Khi[64 * 64], Klo[64 * 64];
    __shared__ u16 Vhi[64 * 64], Vlo[64 * 64];   // [d][kk]
    __shared__ u16 Phi[4][16 * 64], Plo[4][16 * 64];

    const int qt = blockIdx.x, bh = blockIdx.y;
    const int bb = bh >> 4, hh = bh & 15;
    const int tid = threadIdx.x, lane = tid & 63, wid = tid >> 6;
    const int lr = lane & 15, lg = lane >> 4;

    short8 qhi[2], qlo[2];
    {
        const size_t qbase = (size_t)(bb * Ss + qt * 64 + wid * 16 + lr) * Dd + hh * HD;
#pragma unroll
        for (int ks = 0; ks < 2; ++ks) {
            qhi[ks] = *(const short8*)(qhp + qbase + ks * 32 + lg * 8);
            qlo[ks] = *(const short8*)(qlp + qbase + ks * 32 + lg * 8);
        }
    }

    float mrun[4], lrun[4];
    f32x4 oacc[4];
#pragma unroll
    for (int r = 0; r < 4; ++r) { mrun[r] = -1e30f; lrun[r] = 0.f; }
#pragma unroll
    for (int nf = 0; nf < 4; ++nf) oacc[nf] = zf4();

    const int srow = tid >> 2;        // 0..63
    const int sd = (tid & 3) * 16;    // 0,16,32,48

    u16* const PhiW = Phi[wid];
    u16* const PloW = Plo[wid];

    // prefetch tile 0 into registers
    short8 ck0, ck1, cl0, cl1, cv0, cv1, cw0, cw1;
    {
        const size_t krow = (size_t)(bb * Ss + srow) * Dd + hh * HD + sd;
        const size_t vrow = ((size_t)bh * HD + srow) * Ss + sd;
        ck0 = *(const short8*)(khp + krow);
        ck1 = *(const short8*)(khp + krow + 8);
        cl0 = *(const short8*)(klp + krow);
        cl1 = *(const short8*)(klp + krow + 8);
        cv0 = *(const short8*)(vthp + vrow);
        cv1 = *(const short8*)(vthp + vrow + 8);
        cw0 = *(const short8*)(vtlp + vrow);
        cw1 = *(const short8*)(vtlp + vrow + 8);
    }

    for (int kt = 0; kt < Ss / 64; ++kt) {
        __syncthreads();   // all waves done reading previous K/V LDS tile
        *(short8*)(Khi + swzb(srow, sd)) = ck0;
        *(short8*)(Khi + swzb(srow, sd + 8)) = ck1;
        *(short8*)(Klo + swzb(srow, sd)) = cl0;
        *(short8*)(Klo + swzb(srow, sd + 8)) = cl1;
        *(short8*)(Vhi + swzb(srow, sd)) = cv0;
        *(short8*)(Vhi + swzb(srow, sd + 8)) = cv1;
        *(short8*)(Vlo + swzb(srow, sd)) = cw0;
        *(short8*)(Vlo + swzb(srow, sd + 8)) = cw1;
        __syncthreads();   // writes visible

        // issue next-tile loads; latency hides under the compute below
        if (kt < Ss / 64 - 1) {
            const size_t krow = (size_t)(bb * Ss + (kt + 1) * 64 + srow) * Dd + hh * HD + sd;
            const size_t vrow = ((size_t)bh * HD + srow) * Ss + (kt + 1) * 64 + sd;
            ck0 = *(const short8*)(khp + krow);
            ck1 = *(const short8*)(khp + krow + 8);
            cl0 = *(const short8*)(klp + krow);
            cl1 = *(const short8*)(klp + krow + 8);
            cv0 = *(const short8*)(vthp + vrow);
            cv1 = *(const short8*)(vthp + vrow + 8);
            cw0 = *(const short8*)(vtlp + vrow);
            cw1 = *(const short8*)(vtlp + vrow + 8);
        }

        f32x4 sc[4];
#pragma unroll
        for (int nf = 0; nf < 4; ++nf) sc[nf] = zf4();
#pragma unroll
        for (int nf = 0; nf < 4; ++nf)
#pragma unroll
            for (int ks = 0; ks < 2; ++ks) {
                const short8 kh = *(const short8*)(Khi + swzb(nf * 16 + lr, ks * 32 + lg * 8));
                const short8 kl = *(const short8*)(Klo + swzb(nf * 16 + lr, ks * 32 + lg * 8));
                sc[nf] = __builtin_amdgcn_mfma_f32_16x16x32_bf16(qhi[ks], kh, sc[nf], 0, 0, 0);
                sc[nf] = __builtin_amdgcn_mfma_f32_16x16x32_bf16(qhi[ks], kl, sc[nf], 0, 0, 0);
                sc[nf] = __builtin_amdgcn_mfma_f32_16x16x32_bf16(qlo[ks], kh, sc[nf], 0, 0, 0);
                sc[nf] = __builtin_amdgcn_mfma_f32_16x16x32_bf16(qlo[ks], kl, sc[nf], 0, 0, 0);
            }

        float scl[4];
#pragma unroll
        for (int r = 0; r < 4; ++r) {
            float m = fmaxf(fmaxf(sc[0][r], sc[1][r]), fmaxf(sc[2][r], sc[3][r]));
            m = fmaxf(m, __shfl_xor(m, 1));
            m = fmaxf(m, __shfl_xor(m, 2));
            m = fmaxf(m, __shfl_xor(m, 4));
            m = fmaxf(m, __shfl_xor(m, 8));
            const float mn = fmaxf(mrun[r], m);
            scl[r] = __expf(mrun[r] - mn);
            mrun[r] = mn;
            float s = 0.f;
#pragma unroll
            for (int nf = 0; nf < 4; ++nf) {
                const float p = __expf(sc[nf][r] - mn);
                sc[nf][r] = p;
                s += p;
            }
            s += __shfl_xor(s, 1);
            s += __shfl_xor(s, 2);
            s += __shfl_xor(s, 4);
            s += __shfl_xor(s, 8);
            lrun[r] = lrun[r] * scl[r] + s;
        }

#pragma unroll
        for (int nf = 0; nf < 4; ++nf)
#pragma unroll
            for (int r = 0; r < 4; ++r) {
                const float p = sc[nf][r];
                const u16 h = f2b(p);
                const int idx = swzb(lg * 4 + r, nf * 16 + lr);
                PhiW[idx] = h;
                PloW[idx] = f2b(p - b2f(h));
            }

#pragma unroll
        for (int nf = 0; nf < 4; ++nf)
#pragma unroll
            for (int r = 0; r < 4; ++r) oacc[nf][r] *= scl[r];

#pragma unroll
        for (int ks = 0; ks < 2; ++ks) {
            const short8 ph = *(const short8*)(PhiW + swzb(lr, ks * 32 + lg * 8));
            const short8 pl = *(const short8*)(PloW + swzb(lr, ks * 32 + lg * 8));
#pragma unroll
            for (int nf = 0; nf < 4; ++nf) {
                const short8 vh = *(const short8*)(Vhi + swzb(nf * 16 + lr, ks * 32 + lg * 8));
                const short8 vl = *(const short8*)(Vlo + swzb(nf * 16 + lr, ks * 32 + lg * 8));
                oacc[nf] = __builtin_amdgcn_mfma_f32_16x16x32_bf16(ph, vh, oacc[nf], 0, 0, 0);
                oacc[nf] = __builtin_amdgcn_mfma_f32_16x16x32_bf16(ph, vl, oacc[nf], 0, 0, 0);
                oacc[nf] = __builtin_amdgcn_mfma_f32_16x16x32_bf16(pl, vh, oacc[nf], 0, 0, 0);
                oacc[nf] = __builtin_amdgcn_mfma_f32_16x16x32_bf16(pl, vl, oacc[nf], 0, 0, 0);
            }
        }
    }

    // epilogue: 3-split planes (identical chain to split3_kernel)
#pragma unroll
    for (int r = 0; r < 4; ++r) {
        const float inv = 1.f / lrun[r];
        const size_t base = (size_t)(bb * Ss + qt * 64 + wid * 16 + lg * 4 + r) * Dd + hh * HD;
#pragma unroll
        for (int nf = 0; nf < 4; ++nf) {
            const float o = oacc[nf][r] * inv;
            const u16 h = f2b(o);
            const float r1 = o - b2f(h);
            const u16 m = f2b(r1);
            const u16 l = f2b(r1 - b2f(m));
            const size_t off = base + nf * 16 + lr;
            os[off] = h;
            os[PT + off] = m;
            os[2 * PT + off] = l;
        }
    }
}

// ---------------------------------------------------------------------------
DEVI double block_reduce_d(double v, double* sred, int tid) {
#pragma unroll
    for (int off = 32; off > 0; off >>= 1) v += __shfl_down(v, off);
    __syncthreads();
    if ((tid & 63) == 0) sred[tid >> 6] = v;
    __syncthreads();
    return sred[0] + sred[1] + sred[2] + sred[3];
}

// ---------------------------------------------------------------------------
// LN1: x1f = LN(x + aproj)
// ---------------------------------------------------------------------------
__global__ __launch_bounds__(256)
void ln1_kernel(const float* __restrict__ x, const float* __restrict__ ap,
                const float* __restrict__ g, const float* __restrict__ b,
                float* __restrict__ x1f) {
    __shared__ double sred[4];
    const int t = blockIdx.x, tid = threadIdx.x;
    const float4 xv = ((const float4*)(x + (size_t)t * Dd))[tid];
    const float4 av = ((const float4*)(ap + (size_t)t * Dd))[tid];
    const double v0 = (double)xv.x + (double)av.x;
    const double v1 = (double)xv.y + (double)av.y;
    const double v2 = (double)xv.z + (double)av.z;
    const double v3 = (double)xv.w + (double)av.w;
    const double s = block_reduce_d(v0 + v1 + v2 + v3, sred, tid);
    const double mean = s * (1.0 / Dd);
    const double c0 = v0 - mean, c1 = v1 - mean, c2 = v2 - mean, c3 = v3 - mean;
    const double s2 = block_reduce_d(c0 * c0 + c1 * c1 + c2 * c2 + c3 * c3, sred, tid);
    const double rstd = 1.0 / sqrt(s2 * (1.0 / Dd) + 1e-5);
    const float4 gv = ((const float4*)g)[tid];
    const float4 bv = ((const float4*)b)[tid];
    float4 ov;
    ov.x = (float)(c0 * rstd * (double)gv.x + (double)bv.x);
    ov.y = (float)(c1 * rstd * (double)gv.y + (double)bv.y);
    ov.z = (float)(c2 * rstd * (double)gv.z + (double)bv.z);
    ov.w = (float)(c3 * rstd * (double)gv.w + (double)bv.w);
    ((float4*)(x1f + (size_t)t * Dd))[tid] = ov;
}

// ---------------------------------------------------------------------------
// gating stage 1 (fp64)
// ---------------------------------------------------------------------------
__global__ __launch_bounds__(256)
void gate1_kernel(const float* __restrict__ x1f, const float* __restrict__ wg,
                  int* __restrict__ idx1, int* __restrict__ idx2,
                  float* __restrict__ gate1, float* __restrict__ gate2) {
    const int tid = threadIdx.x, lane = tid & 63, wid = tid >> 6;
    const int t = blockIdx.x * 4 + wid;
    double acc[16];
#pragma unroll
    for (int e = 0; e < 16; ++e) acc[e] = 0.0;
    for (int i = 0; i < 16; ++i) {
        const int d = i * 64 + lane;
        const double xv = (double)x1f[(size_t)t * Dd + d];
        const float4* wr = (const float4*)(wg + (size_t)d * 16);
        const float4 w0 = wr[0], w1 = wr[1], w2 = wr[2], w3 = wr[3];
        acc[0] += xv * (double)w0.x;  acc[1] += xv * (double)w0.y;
        acc[2] += xv * (double)w0.z;  acc[3] += xv * (double)w0.w;
        acc[4] += xv * (double)w1.x;  acc[5] += xv * (double)w1.y;
        acc[6] += xv * (double)w1.z;  acc[7] += xv * (double)w1.w;
        acc[8] += xv * (double)w2.x;  acc[9] += xv * (double)w2.y;
        acc[10] += xv * (double)w2.z; acc[11] += xv * (double)w2.w;
        acc[12] += xv * (double)w3.x; acc[13] += xv * (double)w3.y;
        acc[14] += xv * (double)w3.z; acc[15] += xv * (double)w3.w;
    }
#pragma unroll
    for (int e = 0; e < 16; ++e) {
        acc[e] += __shfl_xor(acc[e], 1);
        acc[e] += __shfl_xor(acc[e], 2);
        acc[e] += __shfl_xor(acc[e], 4);
        acc[e] += __shfl_xor(acc[e], 8);
        acc[e] += __shfl_xor(acc[e], 16);
        acc[e] += __shfl_xor(acc[e], 32);
    }
    if (lane == 0) {
        double mx = acc[0];
#pragma unroll
        for (int e = 1; e < 16; ++e) mx = fmax(mx, acc[e]);
        double z = 0.0, ex[16];
#pragma unroll
        for (int e = 0; e < 16; ++e) { ex[e] = exp(acc[e] - mx); z += ex[e]; }
        int b1 = 0; double v1 = acc[0];
#pragma unroll
        for (int e = 1; e < 16; ++e) if (acc[e] > v1) { v1 = acc[e]; b1 = e; }
        int b2 = (b1 == 0) ? 1 : 0; double v2 = acc[b2];
#pragma unroll
        for (int e = 0; e < 16; ++e) if (e != b1 && acc[e] > v2) { v2 = acc[e]; b2 = e; }
        const double rz = 1.0 / z;
        idx1[t] = b1; idx2[t] = b2;
        gate1[t] = (float)(ex[b1] * rz); gate2[t] = (float)(ex[b2] * rz);
    }
}

// ---------------------------------------------------------------------------
// gating stage 2 (single block; per-expert base update parallelized tid<16)
// ---------------------------------------------------------------------------
__global__ __launch_bounds__(256)
void gate2_kernel(const int* __restrict__ idx1, const int* __restrict__ idx2,
                  const float* __restrict__ gate1, const float* __restrict__ gate2,
                  int* __restrict__ p1, int* __restrict__ p2,
                  int* __restrict__ k1, int* __restrict__ k2,
                  float* __restrict__ w1, float* __restrict__ w2) {
    __shared__ int hist[16];
    __shared__ unsigned long long sb1[4][16], sb2[4][16];
    __shared__ int sbase1[16], sbase2[16];
    const int tid = threadIdx.x, lane = tid & 63, wid = tid >> 6;
    if (tid < 16) hist[tid] = 0;
    __syncthreads();
    for (int t = tid; t < Tt; t += 256) atomicAdd(&hist[idx1[t]], 1);
    __syncthreads();
    if (tid < 16) { sbase1[tid] = 0; sbase2[tid] = hist[tid]; }
    __syncthreads();
    const unsigned long long below = (1ULL << lane) - 1ULL;
    for (int ch = 0; ch < Tt / 256; ++ch) {
        const int t = ch * 256 + tid;
        const int a = idx1[t], b = idx2[t];
#pragma unroll
        for (int e = 0; e < 16; ++e) {
            const unsigned long long m1 = __ballot(a == e);
            const unsigned long long m2 = __ballot(b == e);
            if (lane == 0) { sb1[wid][e] = m1; sb2[wid][e] = m2; }
        }
        __syncthreads();
        int r1 = __popcll(sb1[wid][a] & below);
        int r2 = __popcll(sb2[wid][b] & below);
#pragma unroll
        for (int w = 0; w < 4; ++w)
            if (w < wid) { r1 += __popcll(sb1[w][a]); r2 += __popcll(sb2[w][b]); }
        const int loc1 = sbase1[a] + r1, loc2 = sbase2[b] + r2;
        const int kk1 = loc1 < Cap, kk2 = loc2 < Cap;
        const float g1 = kk1 ? gate1[t] : 0.f;
        const float g2 = kk2 ? gate2[t] : 0.f;
        const float dn = fmaxf(g1 + g2, EPSc);
        p1[t] = kk1 ? loc1 : 0;
        p2[t] = kk2 ? loc2 : 0;
        k1[t] = kk1; k2[t] = kk2;
        w1[t] = g1 / dn; w2[t] = g2 / dn;
        __syncthreads();
        if (tid < 16) {
            const int e = tid;
            int c1 = 0, c2 = 0;
#pragma unroll
            for (int w = 0; w < 4; ++w) { c1 += __popcll(sb1[w][e]); c2 += __popcll(sb2[w][e]); }
            sbase1[e] += c1; sbase2[e] += c2;
        }
        __syncthreads();
    }
}

// ---------------------------------------------------------------------------
// dispatch: scatter kept tokens (f32 -> bf16) into [E,C,D] buffers (pre-zeroed)
// ---------------------------------------------------------------------------
__global__ __launch_bounds__(256)
void dispatch_kernel(const float* __restrict__ x1f,
                     const int* __restrict__ i1, const int* __restrict__ p1, const int* __restrict__ k1,
                     const int* __restrict__ i2, const int* __restrict__ p2, const int* __restrict__ k2,
                     u16* __restrict__ buf) {
    const int t = blockIdx.x, tid = threadIdx.x;
    const float4 v = ((const float4*)(x1f + (size_t)t * Dd))[tid];
    u16x4 pw;
    pw[0] = f2b(v.x); pw[1] = f2b(v.y); pw[2] = f2b(v.z); pw[3] = f2b(v.w);
    if (k1[t]) *(u16x4*)(buf + ((size_t)i1[t] * Cap + p1[t]) * Dd + tid * 4) = pw;
    if (k2[t]) *(u16x4*)(buf + ((size_t)i2[t] * Cap + p2[t]) * Dd + tid * 4) = pw;
}

// ---------------------------------------------------------------------------
// combine + residual + LN2 -> d_out (f32)
// ---------------------------------------------------------------------------
__global__ __launch_bounds__(256)
void combine_ln2(const float* __restrict__ x1f, const u16* __restrict__ y,
                 const int* __restrict__ i1, const int* __restrict__ p1, const float* __restrict__ w1,
                 const int* __restrict__ i2, const int* __restrict__ p2, const float* __restrict__ w2,
                 const float* __restrict__ g, const float* __restrict__ b,
                 float* __restrict__ out) {
    __shared__ double sred[4];
    const int t = blockIdx.x, tid = threadIdx.x;
    const size_t r1 = ((size_t)i1[t] * Cap + p1[t]) * Dd;
    const size_t r2 = ((size_t)i2[t] * Cap + p2[t]) * Dd;
    const double a1 = (double)w1[t], a2 = (double)w2[t];
    const u16x4 y1 = *(const u16x4*)(y + r1 + tid * 4);
    const u16x4 y2 = *(const u16x4*)(y + r2 + tid * 4);
    const float4 xv = ((const float4*)(x1f + (size_t)t * Dd))[tid];
    const double v0 = (double)xv.x + a1 * (double)b2f(y1[0]) + a2 * (double)b2f(y2[0]);
    const double v1 = (double)xv.y + a1 * (double)b2f(y1[1]) + a2 * (double)b2f(y2[1]);
    const double v2 = (double)xv.z + a1 * (double)b2f(y1[2]) + a2 * (double)b2f(y2[2]);
    const double v3 = (double)xv.w + a1 * (double)b2f(y1[3]) + a2 * (double)b2f(y2[3]);
    const double s = block_reduce_d(v0 + v1 + v2 + v3, sred, tid);
    const double mean = s * (1.0 / Dd);
    const double c0 = v0 - mean, c1 = v1 - mean, c2 = v2 - mean, c3 = v3 - mean;
    const double s2 = block_reduce_d(c0 * c0 + c1 * c1 + c2 * c2 + c3 * c3, sred, tid);
    const double rstd = 1.0 / sqrt(s2 * (1.0 / Dd) + 1e-5);
    const float4 gv = ((const float4*)g)[tid];
    const float4 bv = ((const float4*)b)[tid];
    float4 ov;
    ov.x = (float)(c0 * rstd * (double)gv.x + (double)bv.x);
    ov.y = (float)(c1 * rstd * (double)gv.y + (double)bv.y);
    ov.z = (float)(c2 * rstd * (double)gv.z + (double)bv.z);
    ov.w = (float)(c3 * rstd * (double)gv.w + (double)bv.w);
    ((float4*)(out + (size_t)t * Dd))[tid] = ov;
}

// ---------------------------------------------------------------------------
extern "C" void kernel_launch(void* const* d_in, const int* in_sizes, int n_in,
                              void* d_out, int out_size, void* d_ws, size_t ws_size,
                              hipStream_t stream) {
    (void)in_sizes; (void)n_in; (void)out_size; (void)ws_size;
    const float* x    = (const float*)d_in[0];
    const float* inW  = (const float*)d_in[1];
    const float* inB  = (const float*)d_in[2];
    const float* outW = (const float*)d_in[3];
    const float* outB = (const float*)d_in[4];
    const float* ln1g = (const float*)d_in[5];
    const float* ln1b = (const float*)d_in[6];
    const float* ln2g = (const float*)d_in[7];
    const float* ln2b = (const float*)d_in[8];
    const float* wg   = (const float*)d_in[9];
    const float* w1   = (const float*)d_in[10];
    const float* b1   = (const float*)d_in[11];
    const float* w2   = (const float*)d_in[12];
    const float* b2   = (const float*)d_in[13];
    float* out = (float*)d_out;

    char* ws = (char*)d_ws;
    const size_t MB = 1024 * 1024;
    // ---- phase-overlapped arena (verified layout, peak 352.4 MiB) ----
    u16*   xs3   = (u16*)(ws + 0);          // [0,48)    dead after QKV gemm
    u16*   inW3  = (u16*)(ws + 48 * MB);    // [48,66)   dead after QKV gemm
    u16*   qh    = (u16*)(ws + 66 * MB);    // [66,82)   dead after attn
    u16*   ql    = (u16*)(ws + 82 * MB);    // [82,98)   dead after attn
    u16*   kh    = (u16*)(ws + 98 * MB);    // [98,114)  dead after attn
    u16*   kl    = (u16*)(ws + 114 * MB);   // [114,130) dead after attn
    u16*   vh    = (u16*)(ws + 130 * MB);   // [130,146) dead after vtrans
    u16*   vl    = (u16*)(ws + 146 * MB);   // [146,162) dead after vtrans
    u16*   vth   = (u16*)(ws + 162 * MB);   // [162,178) dead after attn
    u16*   vtl   = (u16*)(ws + 178 * MB);   // [178,194) dead after attn
    u16*   os3   = (u16*)(ws + 194 * MB);   // [194,242) attn out, dead after OP
    u16*   outW3 = (u16*)(ws + 0);          // [0,6)     over dead xs3, dead after OP
    float* aproj = (float*)(ws + 6 * MB);   // [6,38)    over dead xs3, dead after LN1
    u16*   wt    = (u16*)(ws + 0);          // [0,128)   written post-LN1 (all dead)
    u16*   hbuf  = (u16*)(ws + 128 * MB);   // [128,256) over dead kl-tail/v*/os3
    u16*   ybuf  = (u16*)(ws + 256 * MB);   // [256,288) fresh
    u16*   ebuf  = (u16*)(ws + 288 * MB);   // [288,320) fresh
    float* x1f   = (float*)(ws + 320 * MB); // [320,352) fresh, live till end
    char*  gbase = ws + 352 * MB;           // [352,~352.4) gating arrays
    int*   idx1 = (int*)(gbase + 0 * Tt * 4);
    int*   idx2 = (int*)(gbase + 1 * Tt * 4);
    float* gt1  = (float*)(gbase + 2 * Tt * 4);
    float* gt2  = (float*)(gbase + 3 * Tt * 4);
    int*   p1   = (int*)(gbase + 4 * Tt * 4);
    int*   p2   = (int*)(gbase + 5 * Tt * 4);
    int*   k1   = (int*)(gbase + 6 * Tt * 4);
    int*   k2   = (int*)(gbase + 7 * Tt * 4);
    float* w1c  = (float*)(gbase + 8 * Tt * 4);
    float* w2c  = (float*)(gbase + 9 * Tt * 4);

    const long long nTD = (long long)Tt * Dd;
    const long long nW1 = (long long)D3 * Dd;
    const long long nW2 = (long long)Dd * Dd;

    // 1: split inputs; QKV GEMM (proven gemm_gl) writes split planes
    split3_kernel<<<(int)(nTD / 1024), 256, 0, stream>>>(x, xs3, nTD);
    split3_kernel<<<(int)(nW1 / 1024), 256, 0, stream>>>(inW, inW3, nW1);
    gemm_gl<3, 3><<<dim3(D3 / 128, Tt / 128, 1), 256, 0, stream>>>(
        xs3, inW3, nullptr, inB, Tt, D3, Dd, (size_t)nTD, (size_t)nW1,
        qh, ql, kh, kl, vh, vl);
    // 2: V transpose; attention (bit-identical values, prefetch scheduling)
    vtrans_kernel<<<dim3(Ss / 32, HD / 32, Bz * Hh), 256, 0, stream>>>(vh, vl, vth, vtl);
    attn_mfma<<<dim3(Ss / 64, Bz * Hh), 256, 0, stream>>>(qh, ql, kh, kl, vth, vtl, os3);
    // 3: out-proj (proven gemm_gl, f32 out)
    split3_kernel<<<(int)(nW2 / 1024), 256, 0, stream>>>(outW, outW3, nW2);
    gemm_gl<3, 2><<<dim3(Dd / 128, Tt / 128, 1), 256, 0, stream>>>(
        os3, outW3, aproj, outB, Tt, Dd, Dd, (size_t)nTD, (size_t)nW2,
        nullptr, nullptr, nullptr, nullptr, nullptr, nullptr);
    // 4: LN1
    ln1_kernel<<<Tt, 256, 0, stream>>>(x, aproj, ln1g, ln1b, x1f);
    // 5-6: gating
    gate1_kernel<<<Tt / 4, 256, 0, stream>>>(x1f, wg, idx1, idx2, gt1, gt2);
    gate2_kernel<<<1, 256, 0, stream>>>(idx1, idx2, gt1, gt2, p1, p2, k1, k2, w1c, w2c);
    // 7: dispatch
    hipMemsetAsync(ebuf, 0, (size_t)Ee * Cap * Dd * 2, stream);
    dispatch_kernel<<<Tt, 256, 0, stream>>>(x1f, idx1, p1, k1, idx2, p2, k2, ebuf);
    // 8-11: expert FFN — 256^2 dbuf counted-vmcnt GEMMs + bank swizzle
    tconv64_kernel<<<dim3(DFF / 64, Dd / 64, Ee), 256, 0, stream>>>(w1, wt, Dd, DFF);
    gemm_x2<1><<<dim3(DFF / 256, Cap / 256, Ee), 512, 0, stream>>>(
        ebuf, wt, hbuf, b1, Cap, DFF, Dd,
        (size_t)Cap * Dd, (size_t)DFF * Dd, (size_t)Cap * DFF, DFF);
    tconv64_kernel<<<dim3(Dd / 64, DFF / 64, Ee), 256, 0, stream>>>(w2, wt, DFF, Dd);
    gemm_x2<0><<<dim3(Dd / 256, Cap / 256, Ee), 512, 0, stream>>>(
        hbuf, wt, ybuf, b2, Cap, Dd, DFF,
        (size_t)Cap * DFF, (size_t)Dd * DFF, (size_t)Cap * Dd, Dd);
    // 12: combine + residual + LN2
    combine_ln2<<<Tt, 256, 0, stream>>>(x1f, ybuf, idx1, p1, w1c, idx2, p2, w2c, ln2g, ln2b, out);
}

// Round 12
// 1263.674 us; speedup vs baseline: 1.0141x; 1.0141x over previous
//
#include <hip/hip_runtime.h>
#include <cstdint>

#define DEVI __device__ __forceinline__

typedef short short8 __attribute__((ext_vector_type(8)));
typedef float f32x4 __attribute__((ext_vector_type(4)));
typedef unsigned short u16;
typedef u16 u16x4 __attribute__((ext_vector_type(4)));

static constexpr int Bz = 8, Ss = 1024, Dd = 1024, Hh = 16, HD = 64, DFF = 4096, Ee = 16;
static constexpr int Tt = Bz * Ss;           // 8192 tokens
static constexpr int Cap = (2 * Tt) / Ee;    // 1024 capacity
static constexpr int D3 = 3 * Dd;            // 3072
static constexpr float EPSc = 1.1920929e-07f;
static constexpr size_t PT = (size_t)Tt * Dd;   // plane elements (token-major)

DEVI u16 f2b(float f) {
    union { float f; uint32_t u; } v; v.f = f;
    return (u16)((v.u + 0x7FFFu + ((v.u >> 16) & 1u)) >> 16);
}
DEVI float b2f(u16 h) {
    union { uint32_t u; float f; } v; v.u = ((uint32_t)h) << 16; return v.f;
}
DEVI f32x4 zf4() { f32x4 v; v[0] = 0.f; v[1] = 0.f; v[2] = 0.f; v[3] = 0.f; return v; }

// async global->LDS, 16B per lane. LDS dest must be wave-uniform base + lane*16B.
DEVI void gl16(const u16* g, u16* l) {
    __builtin_amdgcn_global_load_lds(
        (const __attribute__((address_space(1))) void*)g,
        (__attribute__((address_space(3))) void*)l, 16, 0, 0);
}

// swizzled u16 index for [R][64] bf16 tiles (128B rows): byte ^= (row&7)<<4
DEVI int swzb(int row, int col) {
    int byte = (row * 64 + col) * 2;
    byte ^= (row & 7) << 4;
    return byte >> 1;
}

// ---------------------------------------------------------------------------
// split fp32 -> 3 bf16 planes (hi/mid/lo), plane stride = n. n % 1024 == 0.
// ---------------------------------------------------------------------------
__global__ __launch_bounds__(256)
void split3_kernel(const float* __restrict__ in, u16* __restrict__ out, long long n) {
    const long long i = ((long long)blockIdx.x * 256 + threadIdx.x) * 4;
    if (i >= n) return;
    const float4 v = *(const float4*)(in + i);
    const float f[4] = {v.x, v.y, v.z, v.w};
    u16x4 ph, pm, pl;
#pragma unroll
    for (int c = 0; c < 4; ++c) {
        const u16 hi = f2b(f[c]);
        const float r1 = f[c] - b2f(hi);     // exact
        const u16 mi = f2b(r1);
        const float r2 = r1 - b2f(mi);       // exact
        const u16 lo = f2b(r2);
        ph[c] = hi; pm[c] = mi; pl[c] = lo;
    }
    *(u16x4*)(out + i) = ph;
    *(u16x4*)(out + n + i) = pm;
    *(u16x4*)(out + 2 * n + i) = pl;
}

// ---------------------------------------------------------------------------
// transpose + convert, vectorized: in [Z][R][Cc] f32 -> out [Z][Cc][R] bf16
// ---------------------------------------------------------------------------
__global__ __launch_bounds__(256)
void tconv64_kernel(const float* __restrict__ in, u16* __restrict__ out, int R, int Cc) {
    __shared__ u16 tile[64][68];
    const int z = blockIdx.z;
    const int r0 = blockIdx.y * 64, c0 = blockIdx.x * 64;
    const int tr = threadIdx.x >> 4;          // 0..15
    const int tc4 = (threadIdx.x & 15) * 4;   // 0..60
    const float* ip = in + (size_t)z * R * Cc;
#pragma unroll
    for (int i = 0; i < 4; ++i) {
        const int row = tr + i * 16;
        const float4 v = *(const float4*)(ip + (size_t)(r0 + row) * Cc + c0 + tc4);
        u16x4 w;
        w[0] = f2b(v.x); w[1] = f2b(v.y); w[2] = f2b(v.z); w[3] = f2b(v.w);
        *(u16x4*)(&tile[row][tc4]) = w;
    }
    __syncthreads();
    u16* op = out + (size_t)z * R * Cc;
#pragma unroll
    for (int i = 0; i < 4; ++i) {
        const int orow = tr + i * 16;
        u16x4 w;
#pragma unroll
        for (int j = 0; j < 4; ++j) w[j] = tile[tc4 + j][orow];
        *(u16x4*)(op + (size_t)(c0 + orow) * R + r0 + tc4) = w;
    }
}

// ---------------------------------------------------------------------------
// V-plane transpose: vh/vl [Tt][Dd] (per bh: [s][64]) -> vth/vtl [bh][64][Ss]
// ---------------------------------------------------------------------------
__global__ __launch_bounds__(256)
void vtrans_kernel(const u16* __restrict__ vh, const u16* __restrict__ vl,
                   u16* __restrict__ vth, u16* __restrict__ vtl) {
    __shared__ u16 th[32][33], tl[32][33];
    const int bh = blockIdx.z, d0 = blockIdx.y * 32, s0 = blockIdx.x * 32;
    const int bb = bh >> 4, hh = bh & 15;
    const int tr = threadIdx.x >> 5, tc = threadIdx.x & 31;
#pragma unroll
    for (int i = 0; i < 4; ++i) {
        const size_t src = (size_t)(bb * Ss + s0 + tr + i * 8) * Dd + hh * HD + d0 + tc;
        th[tr + i * 8][tc] = vh[src];
        tl[tr + i * 8][tc] = vl[src];
    }
    __syncthreads();
#pragma unroll
    for (int i = 0; i < 4; ++i) {
        const size_t dst = ((size_t)bh * HD + d0 + tr + i * 8) * Ss + s0 + tc;
        vth[dst] = th[tc][tr + i * 8];
        vtl[dst] = tl[tc][tr + i * 8];
    }
}

// ---------------------------------------------------------------------------
// 3-split MFMA BT-GEMM (routing path) — proven structure:
// 128x128 tile, BK=32, 4 waves, single-buffer, global_load_lds, 2 barriers.
// MODE: 2 f32 out, 3 QKV split-plane out. 6 products, bit-stable chain.
// ---------------------------------------------------------------------------
template <int SPLITS, int MODE>
__global__ __launch_bounds__(256)
void gemm_gl(const u16* __restrict__ A, const u16* __restrict__ Bt, void* __restrict__ Cout,
             const float* __restrict__ bias, int M, int N, int K,
             size_t psA, size_t psB,
             u16* __restrict__ qh, u16* __restrict__ ql,
             u16* __restrict__ kh, u16* __restrict__ kl,
             u16* __restrict__ vh, u16* __restrict__ vl) {
    __shared__ u16 As[SPLITS * 128 * 32];
    __shared__ u16 Bs[SPLITS * 128 * 32];
    const int tid = threadIdx.x;
    const int lane = tid & 63, wid = tid >> 6;
    const int wm = wid >> 1, wn = wid & 1;
    const int m0 = blockIdx.y * 128, n0 = blockIdx.x * 128;
    const int lr = lane & 15, lg = lane >> 4;
    const int lrow = lane >> 2;          // 0..15
    const int lcol = (lane & 3) * 8;     // 0,8,16,24

    f32x4 acc[4][4];
#pragma unroll
    for (int i = 0; i < 4; ++i)
#pragma unroll
        for (int j = 0; j < 4; ++j) acc[i][j] = zf4();

    for (int kt = 0; kt < K; kt += 32) {
#pragma unroll
        for (int p = 0; p < SPLITS; ++p) {
#pragma unroll
            for (int c = 0; c < 2; ++c) {
                const int r0 = wid * 32 + c * 16;
                gl16(A + p * psA + (size_t)(m0 + r0 + lrow) * K + kt + lcol,
                     As + p * 4096 + r0 * 32 + lane * 8);
                gl16(Bt + p * psB + (size_t)(n0 + r0 + lrow) * K + kt + lcol,
                     Bs + p * 4096 + r0 * 32 + lane * 8);
            }
        }
        __syncthreads();

        short8 af[SPLITS][4];
#pragma unroll
        for (int p = 0; p < SPLITS; ++p)
#pragma unroll
            for (int i = 0; i < 4; ++i)
                af[p][i] = *(const short8*)(As + p * 4096 + (wm * 64 + i * 16 + lr) * 32 + lg * 8);

#pragma unroll
        for (int bp = 0; bp < SPLITS; ++bp) {
            short8 bf[4];
#pragma unroll
            for (int j = 0; j < 4; ++j)
                bf[j] = *(const short8*)(Bs + bp * 4096 + (wn * 64 + j * 16 + lr) * 32 + lg * 8);
#pragma unroll
            for (int ap = 0; ap + bp < SPLITS; ++ap)
#pragma unroll
                for (int i = 0; i < 4; ++i)
#pragma unroll
                    for (int j = 0; j < 4; ++j)
                        acc[i][j] = __builtin_amdgcn_mfma_f32_16x16x32_bf16(af[ap][i], bf[j], acc[i][j], 0, 0, 0);
        }
        __syncthreads();
    }

    const int r4 = lg * 4;
    const int region = n0 >> 10;   // MODE 3: 0=Q,1=K,2=V (uniform per block)
#pragma unroll
    for (int j = 0; j < 4; ++j) {
        const int col = n0 + wn * 64 + j * 16 + lr;
        const float bv = bias[col];
#pragma unroll
        for (int i = 0; i < 4; ++i) {
#pragma unroll
            for (int r = 0; r < 4; ++r) {
                const int rowg = m0 + wm * 64 + i * 16 + r4 + r;
                float v = acc[i][j][r] + bv;
                if (MODE == 2) {
                    ((float*)Cout)[(size_t)rowg * N + col] = v;
                } else {
                    const size_t off = (size_t)rowg * Dd + (col & 1023);
                    if (region == 0) {
                        const float fs = v * 0.125f;
                        const u16 h = f2b(fs);
                        qh[off] = h; ql[off] = f2b(fs - b2f(h));
                    } else if (region == 1) {
                        const u16 h = f2b(v);
                        kh[off] = h; kl[off] = f2b(v - b2f(h));
                    } else {
                        const u16 h = f2b(v);
                        vh[off] = h; vl[off] = f2b(v - b2f(h));
                    }
                }
            }
        }
    }
}

// ---------------------------------------------------------------------------
// Expert GEMM, 256x256 tile, BK=64, 8 waves, double-buffered LDS,
// counted vmcnt(8) + XOR bank swizzle (validated rounds 7-11).
// ---------------------------------------------------------------------------
template <int RELU>
__global__ __launch_bounds__(512)
void gemm_x2(const u16* __restrict__ A, const u16* __restrict__ Bt, u16* __restrict__ Cout,
             const float* __restrict__ bias, int M, int N, int K,
             size_t sA, size_t sB, size_t sC, int sBias) {
    __shared__ u16 lds[2][2][256 * 64];   // 128 KiB
    const int tid = threadIdx.x, lane = tid & 63, wid = tid >> 6;
    const int wm = wid >> 2, wn = wid & 3;
    const int lr = lane & 15, lg = lane >> 4;
    const int m0 = blockIdx.y * 256, n0 = blockIdx.x * 256;
    const int e = blockIdx.z;
    const u16* Ab = A + (size_t)e * sA;
    const u16* Bb = Bt + (size_t)e * sB;

    const int srow = wid * 8 + (lane >> 3);
    const int sscol = (((lane & 7) ^ ((lane >> 3) & 7))) * 8;

    f32x4 acc[8][4];
#pragma unroll
    for (int i = 0; i < 8; ++i)
#pragma unroll
        for (int j = 0; j < 4; ++j) acc[i][j] = zf4();

#define STAGE_X2(b, kt)                                                              \
    {                                                                                \
        _Pragma("unroll")                                                            \
        for (int c = 0; c < 4; ++c)                                                  \
            gl16(Ab + (size_t)(m0 + c * 64 + srow) * K + (kt) + sscol,               \
                 &lds[b][0][(c * 64 + srow) * 64 + (lane & 7) * 8]);                 \
        _Pragma("unroll")                                                            \
        for (int c = 0; c < 4; ++c)                                                  \
            gl16(Bb + (size_t)(n0 + c * 64 + srow) * K + (kt) + sscol,               \
                 &lds[b][1][(c * 64 + srow) * 64 + (lane & 7) * 8]);                 \
    }

#define COMPUTE_X2(b)                                                                \
    {                                                                                \
        _Pragma("unroll")                                                            \
        for (int ks = 0; ks < 2; ++ks) {                                             \
            short8 af[8], bf[4];                                                     \
            _Pragma("unroll")                                                        \
            for (int i = 0; i < 8; ++i)                                              \
                af[i] = *(const short8*)(&lds[b][0][(wm * 128 + i * 16 + lr) * 64 +  \
                                                    (((ks * 4 + lg) ^ (lr & 7)) * 8)]); \
            _Pragma("unroll")                                                        \
            for (int j = 0; j < 4; ++j)                                              \
                bf[j] = *(const short8*)(&lds[b][1][(wn * 64 + j * 16 + lr) * 64 +   \
                                                    (((ks * 4 + lg) ^ (lr & 7)) * 8)]); \
            _Pragma("unroll")                                                        \
            for (int i = 0; i < 8; ++i)                                              \
                _Pragma("unroll")                                                    \
                for (int j = 0; j < 4; ++j)                                          \
                    acc[i][j] = __builtin_amdgcn_mfma_f32_16x16x32_bf16(af[i], bf[j], acc[i][j], 0, 0, 0); \
        }                                                                            \
    }

    const int nt = K >> 6;
    STAGE_X2(0, 0)
    for (int t = 0; t < nt - 1; ++t) {
        const int cur = t & 1;
        STAGE_X2(cur ^ 1, (t + 1) * 64)
        asm volatile("s_waitcnt vmcnt(8)" ::: "memory");
        __builtin_amdgcn_s_barrier();
        COMPUTE_X2(cur)
        asm volatile("s_waitcnt lgkmcnt(0)" ::: "memory");
        __builtin_amdgcn_s_barrier();
    }
    asm volatile("s_waitcnt vmcnt(0)" ::: "memory");
    __builtin_amdgcn_s_barrier();
    COMPUTE_X2((nt - 1) & 1)

#undef STAGE_X2
#undef COMPUTE_X2

    const int r4 = lg * 4;
#pragma unroll
    for (int j = 0; j < 4; ++j) {
        const int col = n0 + wn * 64 + j * 16 + lr;
        const float bv = bias[(size_t)e * sBias + col];
#pragma unroll
        for (int i = 0; i < 8; ++i) {
#pragma unroll
            for (int r = 0; r < 4; ++r) {
                const int rowg = m0 + wm * 128 + i * 16 + r4 + r;
                float v = acc[i][j][r] + bv;
                if (RELU) v = fmaxf(v, 0.f);
                Cout[(size_t)e * sC + (size_t)rowg * N + col] = f2b(v);
            }
        }
    }
}

// ---------------------------------------------------------------------------
// Split-bf16 MFMA flash attention — REVERTED to the validated round-6/9 form
// (loads at loop top; implicit compiler/TLP overlap; 84 VGPR).
// ---------------------------------------------------------------------------
__global__ __launch_bounds__(256)
void attn_mfma(const u16* __restrict__ qhp, const u16* __restrict__ qlp,
               const u16* __restrict__ khp, const u16* __restrict__ klp,
               const u16* __restrict__ vthp, const u16* __restrict__ vtlp,
               u16* __restrict__ os) {
    __shared__ u16 Khi[64 * 64], Klo[64 * 64];
    __shared__ u16 Vhi[64 * 64], Vlo[64 * 64];   // [d][kk]
    __shared__ u16 Phi[4][16 * 64], Plo[4][16 * 64];

    const int qt = blockIdx.x, bh = blockIdx.y;
    const int bb = bh >> 4, hh = bh & 15;
    const int tid = threadIdx.x, lane = tid & 63, wid = tid >> 6;
    const int lr = lane & 15, lg = lane >> 4;

    short8 qhi[2], qlo[2];
    {
        const size_t qbase = (size_t)(bb * Ss + qt * 64 + wid * 16 + lr) * Dd + hh * HD;
#pragma unroll
        for (int ks = 0; ks < 2; ++ks) {
            qhi[ks] = *(const short8*)(qhp + qbase + ks * 32 + lg * 8);
            qlo[ks] = *(const short8*)(qlp + qbase + ks * 32 + lg * 8);
        }
    }

    float mrun[4], lrun[4];
    f32x4 oacc[4];
#pragma unroll
    for (int r = 0; r < 4; ++r) { mrun[r] = -1e30f; lrun[r] = 0.f; }
#pragma unroll
    for (int nf = 0; nf < 4; ++nf) oacc[nf] = zf4();

    const int srow = tid >> 2;        // 0..63
    const int sd = (tid & 3) * 16;    // 0,16,32,48

    u16* const PhiW = Phi[wid];
    u16* const PloW = Plo[wid];

    for (int kt = 0; kt < Ss / 64; ++kt) {
        const size_t krow = (size_t)(bb * Ss + kt * 64 + srow) * Dd + hh * HD + sd;
        const short8 k0 = *(const short8*)(khp + krow);
        const short8 k1 = *(const short8*)(khp + krow + 8);
        const short8 l0 = *(const short8*)(klp + krow);
        const short8 l1 = *(const short8*)(klp + krow + 8);
        const size_t vrow = ((size_t)bh * HD + srow) * Ss + kt * 64 + sd;
        const short8 v0 = *(const short8*)(vthp + vrow);
        const short8 v1 = *(const short8*)(vthp + vrow + 8);
        const short8 w0 = *(const short8*)(vtlp + vrow);
        const short8 w1 = *(const short8*)(vtlp + vrow + 8);
        __syncthreads();
        *(short8*)(Khi + swzb(srow, sd)) = k0;
        *(short8*)(Khi + swzb(srow, sd + 8)) = k1;
        *(short8*)(Klo + swzb(srow, sd)) = l0;
        *(short8*)(Klo + swzb(srow, sd + 8)) = l1;
        *(short8*)(Vhi + swzb(srow, sd)) = v0;
        *(short8*)(Vhi + swzb(srow, sd + 8)) = v1;
        *(short8*)(Vlo + swzb(srow, sd)) = w0;
        *(short8*)(Vlo + swzb(srow, sd + 8)) = w1;
        __syncthreads();

        f32x4 sc[4];
#pragma unroll
        for (int nf = 0; nf < 4; ++nf) sc[nf] = zf4();
#pragma unroll
        for (int nf = 0; nf < 4; ++nf)
#pragma unroll
            for (int ks = 0; ks < 2; ++ks) {
                const short8 kh = *(const short8*)(Khi + swzb(nf * 16 + lr, ks * 32 + lg * 8));
                const short8 kl = *(const short8*)(Klo + swzb(nf * 16 + lr, ks * 32 + lg * 8));
                sc[nf] = __builtin_amdgcn_mfma_f32_16x16x32_bf16(qhi[ks], kh, sc[nf], 0, 0, 0);
                sc[nf] = __builtin_amdgcn_mfma_f32_16x16x32_bf16(qhi[ks], kl, sc[nf], 0, 0, 0);
                sc[nf] = __builtin_amdgcn_mfma_f32_16x16x32_bf16(qlo[ks], kh, sc[nf], 0, 0, 0);
                sc[nf] = __builtin_amdgcn_mfma_f32_16x16x32_bf16(qlo[ks], kl, sc[nf], 0, 0, 0);
            }

        float scl[4];
#pragma unroll
        for (int r = 0; r < 4; ++r) {
            float m = fmaxf(fmaxf(sc[0][r], sc[1][r]), fmaxf(sc[2][r], sc[3][r]));
            m = fmaxf(m, __shfl_xor(m, 1));
            m = fmaxf(m, __shfl_xor(m, 2));
            m = fmaxf(m, __shfl_xor(m, 4));
            m = fmaxf(m, __shfl_xor(m, 8));
            const float mn = fmaxf(mrun[r], m);
            scl[r] = __expf(mrun[r] - mn);
            mrun[r] = mn;
            float s = 0.f;
#pragma unroll
            for (int nf = 0; nf < 4; ++nf) {
                const float p = __expf(sc[nf][r] - mn);
                sc[nf][r] = p;
                s += p;
            }
            s += __shfl_xor(s, 1);
            s += __shfl_xor(s, 2);
            s += __shfl_xor(s, 4);
            s += __shfl_xor(s, 8);
            lrun[r] = lrun[r] * scl[r] + s;
        }

#pragma unroll
        for (int nf = 0; nf < 4; ++nf)
#pragma unroll
            for (int r = 0; r < 4; ++r) {
                const float p = sc[nf][r];
                const u16 h = f2b(p);
                const int idx = swzb(lg * 4 + r, nf * 16 + lr);
                PhiW[idx] = h;
                PloW[idx] = f2b(p - b2f(h));
            }

#pragma unroll
        for (int nf = 0; nf < 4; ++nf)
#pragma unroll
            for (int r = 0; r < 4; ++r) oacc[nf][r] *= scl[r];

#pragma unroll
        for (int ks = 0; ks < 2; ++ks) {
            const short8 ph = *(const short8*)(PhiW + swzb(lr, ks * 32 + lg * 8));
            const short8 pl = *(const short8*)(PloW + swzb(lr, ks * 32 + lg * 8));
#pragma unroll
            for (int nf = 0; nf < 4; ++nf) {
                const short8 vh = *(const short8*)(Vhi + swzb(nf * 16 + lr, ks * 32 + lg * 8));
                const short8 vl = *(const short8*)(Vlo + swzb(nf * 16 + lr, ks * 32 + lg * 8));
                oacc[nf] = __builtin_amdgcn_mfma_f32_16x16x32_bf16(ph, vh, oacc[nf], 0, 0, 0);
                oacc[nf] = __builtin_amdgcn_mfma_f32_16x16x32_bf16(ph, vl, oacc[nf], 0, 0, 0);
                oacc[nf] = __builtin_amdgcn_mfma_f32_16x16x32_bf16(pl, vh, oacc[nf], 0, 0, 0);
                oacc[nf] = __builtin_amdgcn_mfma_f32_16x16x32_bf16(pl, vl, oacc[nf], 0, 0, 0);
            }
        }
    }

    // epilogue: 3-split planes (identical chain to split3_kernel)
#pragma unroll
    for (int r = 0; r < 4; ++r) {
        const float inv = 1.f / lrun[r];
        const size_t base = (size_t)(bb * Ss + qt * 64 + wid * 16 + lg * 4 + r) * Dd + hh * HD;
#pragma unroll
        for (int nf = 0; nf < 4; ++nf) {
            const float o = oacc[nf][r] * inv;
            const u16 h = f2b(o);
            const float r1 = o - b2f(h);
            const u16 m = f2b(r1);
            const u16 l = f2b(r1 - b2f(m));
            const size_t off = base + nf * 16 + lr;
            os[off] = h;
            os[PT + off] = m;
            os[2 * PT + off] = l;
        }
    }
}

// ---------------------------------------------------------------------------
DEVI double block_reduce_d(double v, double* sred, int tid) {
#pragma unroll
    for (int off = 32; off > 0; off >>= 1) v += __shfl_down(v, off);
    __syncthreads();
    if ((tid & 63) == 0) sred[tid >> 6] = v;
    __syncthreads();
    return sred[0] + sred[1] + sred[2] + sred[3];
}

// ---------------------------------------------------------------------------
// LN1: x1f = LN(x + aproj)
// ---------------------------------------------------------------------------
__global__ __launch_bounds__(256)
void ln1_kernel(const float* __restrict__ x, const float* __restrict__ ap,
                const float* __restrict__ g, const float* __restrict__ b,
                float* __restrict__ x1f) {
    __shared__ double sred[4];
    const int t = blockIdx.x, tid = threadIdx.x;
    const float4 xv = ((const float4*)(x + (size_t)t * Dd))[tid];
    const float4 av = ((const float4*)(ap + (size_t)t * Dd))[tid];
    const double v0 = (double)xv.x + (double)av.x;
    const double v1 = (double)xv.y + (double)av.y;
    const double v2 = (double)xv.z + (double)av.z;
    const double v3 = (double)xv.w + (double)av.w;
    const double s = block_reduce_d(v0 + v1 + v2 + v3, sred, tid);
    const double mean = s * (1.0 / Dd);
    const double c0 = v0 - mean, c1 = v1 - mean, c2 = v2 - mean, c3 = v3 - mean;
    const double s2 = block_reduce_d(c0 * c0 + c1 * c1 + c2 * c2 + c3 * c3, sred, tid);
    const double rstd = 1.0 / sqrt(s2 * (1.0 / Dd) + 1e-5);
    const float4 gv = ((const float4*)g)[tid];
    const float4 bv = ((const float4*)b)[tid];
    float4 ov;
    ov.x = (float)(c0 * rstd * (double)gv.x + (double)bv.x);
    ov.y = (float)(c1 * rstd * (double)gv.y + (double)bv.y);
    ov.z = (float)(c2 * rstd * (double)gv.z + (double)bv.z);
    ov.w = (float)(c3 * rstd * (double)gv.w + (double)bv.w);
    ((float4*)(x1f + (size_t)t * Dd))[tid] = ov;
}

// ---------------------------------------------------------------------------
// gating stage 1 (fp64)
// ---------------------------------------------------------------------------
__global__ __launch_bounds__(256)
void gate1_kernel(const float* __restrict__ x1f, const float* __restrict__ wg,
                  int* __restrict__ idx1, int* __restrict__ idx2,
                  float* __restrict__ gate1, float* __restrict__ gate2) {
    const int tid = threadIdx.x, lane = tid & 63, wid = tid >> 6;
    const int t = blockIdx.x * 4 + wid;
    double acc[16];
#pragma unroll
    for (int e = 0; e < 16; ++e) acc[e] = 0.0;
    for (int i = 0; i < 16; ++i) {
        const int d = i * 64 + lane;
        const double xv = (double)x1f[(size_t)t * Dd + d];
        const float4* wr = (const float4*)(wg + (size_t)d * 16);
        const float4 w0 = wr[0], w1 = wr[1], w2 = wr[2], w3 = wr[3];
        acc[0] += xv * (double)w0.x;  acc[1] += xv * (double)w0.y;
        acc[2] += xv * (double)w0.z;  acc[3] += xv * (double)w0.w;
        acc[4] += xv * (double)w1.x;  acc[5] += xv * (double)w1.y;
        acc[6] += xv * (double)w1.z;  acc[7] += xv * (double)w1.w;
        acc[8] += xv * (double)w2.x;  acc[9] += xv * (double)w2.y;
        acc[10] += xv * (double)w2.z; acc[11] += xv * (double)w2.w;
        acc[12] += xv * (double)w3.x; acc[13] += xv * (double)w3.y;
        acc[14] += xv * (double)w3.z; acc[15] += xv * (double)w3.w;
    }
#pragma unroll
    for (int e = 0; e < 16; ++e) {
        acc[e] += __shfl_xor(acc[e], 1);
        acc[e] += __shfl_xor(acc[e], 2);
        acc[e] += __shfl_xor(acc[e], 4);
        acc[e] += __shfl_xor(acc[e], 8);
        acc[e] += __shfl_xor(acc[e], 16);
        acc[e] += __shfl_xor(acc[e], 32);
    }
    if (lane == 0) {
        double mx = acc[0];
#pragma unroll
        for (int e = 1; e < 16; ++e) mx = fmax(mx, acc[e]);
        double z = 0.0, ex[16];
#pragma unroll
        for (int e = 0; e < 16; ++e) { ex[e] = exp(acc[e] - mx); z += ex[e]; }
        int b1 = 0; double v1 = acc[0];
#pragma unroll
        for (int e = 1; e < 16; ++e) if (acc[e] > v1) { v1 = acc[e]; b1 = e; }
        int b2 = (b1 == 0) ? 1 : 0; double v2 = acc[b2];
#pragma unroll
        for (int e = 0; e < 16; ++e) if (e != b1 && acc[e] > v2) { v2 = acc[e]; b2 = e; }
        const double rz = 1.0 / z;
        idx1[t] = b1; idx2[t] = b2;
        gate1[t] = (float)(ex[b1] * rz); gate2[t] = (float)(ex[b2] * rz);
    }
}

// ---------------------------------------------------------------------------
// gating stage 2 (single block; per-expert base update parallelized tid<16)
// ---------------------------------------------------------------------------
__global__ __launch_bounds__(256)
void gate2_kernel(const int* __restrict__ idx1, const int* __restrict__ idx2,
                  const float* __restrict__ gate1, const float* __restrict__ gate2,
                  int* __restrict__ p1, int* __restrict__ p2,
                  int* __restrict__ k1, int* __restrict__ k2,
                  float* __restrict__ w1, float* __restrict__ w2) {
    __shared__ int hist[16];
    __shared__ unsigned long long sb1[4][16], sb2[4][16];
    __shared__ int sbase1[16], sbase2[16];
    const int tid = threadIdx.x, lane = tid & 63, wid = tid >> 6;
    if (tid < 16) hist[tid] = 0;
    __syncthreads();
    for (int t = tid; t < Tt; t += 256) atomicAdd(&hist[idx1[t]], 1);
    __syncthreads();
    if (tid < 16) { sbase1[tid] = 0; sbase2[tid] = hist[tid]; }
    __syncthreads();
    const unsigned long long below = (1ULL << lane) - 1ULL;
    for (int ch = 0; ch < Tt / 256; ++ch) {
        const int t = ch * 256 + tid;
        const int a = idx1[t], b = idx2[t];
#pragma unroll
        for (int e = 0; e < 16; ++e) {
            const unsigned long long m1 = __ballot(a == e);
            const unsigned long long m2 = __ballot(b == e);
            if (lane == 0) { sb1[wid][e] = m1; sb2[wid][e] = m2; }
        }
        __syncthreads();
        int r1 = __popcll(sb1[wid][a] & below);
        int r2 = __popcll(sb2[wid][b] & below);
#pragma unroll
        for (int w = 0; w < 4; ++w)
            if (w < wid) { r1 += __popcll(sb1[w][a]); r2 += __popcll(sb2[w][b]); }
        const int loc1 = sbase1[a] + r1, loc2 = sbase2[b] + r2;
        const int kk1 = loc1 < Cap, kk2 = loc2 < Cap;
        const float g1 = kk1 ? gate1[t] : 0.f;
        const float g2 = kk2 ? gate2[t] : 0.f;
        const float dn = fmaxf(g1 + g2, EPSc);
        p1[t] = kk1 ? loc1 : 0;
        p2[t] = kk2 ? loc2 : 0;
        k1[t] = kk1; k2[t] = kk2;
        w1[t] = g1 / dn; w2[t] = g2 / dn;
        __syncthreads();
        if (tid < 16) {
            const int e = tid;
            int c1 = 0, c2 = 0;
#pragma unroll
            for (int w = 0; w < 4; ++w) { c1 += __popcll(sb1[w][e]); c2 += __popcll(sb2[w][e]); }
            sbase1[e] += c1; sbase2[e] += c2;
        }
        __syncthreads();
    }
}

// ---------------------------------------------------------------------------
// dispatch: scatter kept tokens (f32 -> bf16) into [E,C,D] buffers (pre-zeroed)
// ---------------------------------------------------------------------------
__global__ __launch_bounds__(256)
void dispatch_kernel(const float* __restrict__ x1f,
                     const int* __restrict__ i1, const int* __restrict__ p1, const int* __restrict__ k1,
                     const int* __restrict__ i2, const int* __restrict__ p2, const int* __restrict__ k2,
                     u16* __restrict__ buf) {
    const int t = blockIdx.x, tid = threadIdx.x;
    const float4 v = ((const float4*)(x1f + (size_t)t * Dd))[tid];
    u16x4 pw;
    pw[0] = f2b(v.x); pw[1] = f2b(v.y); pw[2] = f2b(v.z); pw[3] = f2b(v.w);
    if (k1[t]) *(u16x4*)(buf + ((size_t)i1[t] * Cap + p1[t]) * Dd + tid * 4) = pw;
    if (k2[t]) *(u16x4*)(buf + ((size_t)i2[t] * Cap + p2[t]) * Dd + tid * 4) = pw;
}

// ---------------------------------------------------------------------------
// combine + residual + LN2 -> d_out (f32)
// ---------------------------------------------------------------------------
__global__ __launch_bounds__(256)
void combine_ln2(const float* __restrict__ x1f, const u16* __restrict__ y,
                 const int* __restrict__ i1, const int* __restrict__ p1, const float* __restrict__ w1,
                 const int* __restrict__ i2, const int* __restrict__ p2, const float* __restrict__ w2,
                 const float* __restrict__ g, const float* __restrict__ b,
                 float* __restrict__ out) {
    __shared__ double sred[4];
    const int t = blockIdx.x, tid = threadIdx.x;
    const size_t r1 = ((size_t)i1[t] * Cap + p1[t]) * Dd;
    const size_t r2 = ((size_t)i2[t] * Cap + p2[t]) * Dd;
    const double a1 = (double)w1[t], a2 = (double)w2[t];
    const u16x4 y1 = *(const u16x4*)(y + r1 + tid * 4);
    const u16x4 y2 = *(const u16x4*)(y + r2 + tid * 4);
    const float4 xv = ((const float4*)(x1f + (size_t)t * Dd))[tid];
    const double v0 = (double)xv.x + a1 * (double)b2f(y1[0]) + a2 * (double)b2f(y2[0]);
    const double v1 = (double)xv.y + a1 * (double)b2f(y1[1]) + a2 * (double)b2f(y2[1]);
    const double v2 = (double)xv.z + a1 * (double)b2f(y1[2]) + a2 * (double)b2f(y2[2]);
    const double v3 = (double)xv.w + a1 * (double)b2f(y1[3]) + a2 * (double)b2f(y2[3]);
    const double s = block_reduce_d(v0 + v1 + v2 + v3, sred, tid);
    const double mean = s * (1.0 / Dd);
    const double c0 = v0 - mean, c1 = v1 - mean, c2 = v2 - mean, c3 = v3 - mean;
    const double s2 = block_reduce_d(c0 * c0 + c1 * c1 + c2 * c2 + c3 * c3, sred, tid);
    const double rstd = 1.0 / sqrt(s2 * (1.0 / Dd) + 1e-5);
    const float4 gv = ((const float4*)g)[tid];
    const float4 bv = ((const float4*)b)[tid];
    float4 ov;
    ov.x = (float)(c0 * rstd * (double)gv.x + (double)bv.x);
    ov.y = (float)(c1 * rstd * (double)gv.y + (double)bv.y);
    ov.z = (float)(c2 * rstd * (double)gv.z + (double)bv.z);
    ov.w = (float)(c3 * rstd * (double)gv.w + (double)bv.w);
    ((float4*)(out + (size_t)t * Dd))[tid] = ov;
}

// ---------------------------------------------------------------------------
extern "C" void kernel_launch(void* const* d_in, const int* in_sizes, int n_in,
                              void* d_out, int out_size, void* d_ws, size_t ws_size,
                              hipStream_t stream) {
    (void)in_sizes; (void)n_in; (void)out_size; (void)ws_size;
    const float* x    = (const float*)d_in[0];
    const float* inW  = (const float*)d_in[1];
    const float* inB  = (const float*)d_in[2];
    const float* outW = (const float*)d_in[3];
    const float* outB = (const float*)d_in[4];
    const float* ln1g = (const float*)d_in[5];
    const float* ln1b = (const float*)d_in[6];
    const float* ln2g = (const float*)d_in[7];
    const float* ln2b = (const float*)d_in[8];
    const float* wg   = (const float*)d_in[9];
    const float* w1   = (const float*)d_in[10];
    const float* b1   = (const float*)d_in[11];
    const float* w2   = (const float*)d_in[12];
    const float* b2   = (const float*)d_in[13];
    float* out = (float*)d_out;

    char* ws = (char*)d_ws;
    const size_t MB = 1024 * 1024;
    // ---- phase-overlapped arena (verified layout, peak 352.4 MiB) ----
    u16*   xs3   = (u16*)(ws + 0);          // [0,48)    dead after QKV gemm
    u16*   inW3  = (u16*)(ws + 48 * MB);    // [48,66)   dead after QKV gemm
    u16*   qh    = (u16*)(ws + 66 * MB);    // [66,82)   dead after attn
    u16*   ql    = (u16*)(ws + 82 * MB);    // [82,98)   dead after attn
    u16*   kh    = (u16*)(ws + 98 * MB);    // [98,114)  dead after attn
    u16*   kl    = (u16*)(ws + 114 * MB);   // [114,130) dead after attn
    u16*   vh    = (u16*)(ws + 130 * MB);   // [130,146) dead after vtrans
    u16*   vl    = (u16*)(ws + 146 * MB);   // [146,162) dead after vtrans
    u16*   vth   = (u16*)(ws + 162 * MB);   // [162,178) dead after attn
    u16*   vtl   = (u16*)(ws + 178 * MB);   // [178,194) dead after attn
    u16*   os3   = (u16*)(ws + 194 * MB);   // [194,242) attn out, dead after OP
    u16*   outW3 = (u16*)(ws + 0);          // [0,6)     over dead xs3, dead after OP
    float* aproj = (float*)(ws + 6 * MB);   // [6,38)    over dead xs3, dead after LN1
    u16*   wt    = (u16*)(ws + 0);          // [0,128)   written post-LN1 (all dead)
    u16*   hbuf  = (u16*)(ws + 128 * MB);   // [128,256) over dead kl-tail/v*/os3
    u16*   ybuf  = (u16*)(ws + 256 * MB);   // [256,288) fresh
    u16*   ebuf  = (u16*)(ws + 288 * MB);   // [288,320) fresh
    float* x1f   = (float*)(ws + 320 * MB); // [320,352) fresh, live till end
    char*  gbase = ws + 352 * MB;           // [352,~352.4) gating arrays
    int*   idx1 = (int*)(gbase + 0 * Tt * 4);
    int*   idx2 = (int*)(gbase + 1 * Tt * 4);
    float* gt1  = (float*)(gbase + 2 * Tt * 4);
    float* gt2  = (float*)(gbase + 3 * Tt * 4);
    int*   p1   = (int*)(gbase + 4 * Tt * 4);
    int*   p2   = (int*)(gbase + 5 * Tt * 4);
    int*   k1   = (int*)(gbase + 6 * Tt * 4);
    int*   k2   = (int*)(gbase + 7 * Tt * 4);
    float* w1c  = (float*)(gbase + 8 * Tt * 4);
    float* w2c  = (float*)(gbase + 9 * Tt * 4);

    const long long nTD = (long long)Tt * Dd;
    const long long nW1 = (long long)D3 * Dd;
    const long long nW2 = (long long)Dd * Dd;

    // 1: split inputs; QKV GEMM (proven gemm_gl) writes split planes
    split3_kernel<<<(int)(nTD / 1024), 256, 0, stream>>>(x, xs3, nTD);
    split3_kernel<<<(int)(nW1 / 1024), 256, 0, stream>>>(inW, inW3, nW1);
    gemm_gl<3, 3><<<dim3(D3 / 128, Tt / 128, 1), 256, 0, stream>>>(
        xs3, inW3, nullptr, inB, Tt, D3, Dd, (size_t)nTD, (size_t)nW1,
        qh, ql, kh, kl, vh, vl);
    // 2: V transpose; attention (validated round-6/9 kernel)
    vtrans_kernel<<<dim3(Ss / 32, HD / 32, Bz * Hh), 256, 0, stream>>>(vh, vl, vth, vtl);
    attn_mfma<<<dim3(Ss / 64, Bz * Hh), 256, 0, stream>>>(qh, ql, kh, kl, vth, vtl, os3);
    // 3: out-proj (proven gemm_gl, f32 out)
    split3_kernel<<<(int)(nW2 / 1024), 256, 0, stream>>>(outW, outW3, nW2);
    gemm_gl<3, 2><<<dim3(Dd / 128, Tt / 128, 1), 256, 0, stream>>>(
        os3, outW3, aproj, outB, Tt, Dd, Dd, (size_t)nTD, (size_t)nW2,
        nullptr, nullptr, nullptr, nullptr, nullptr, nullptr);
    // 4: LN1
    ln1_kernel<<<Tt, 256, 0, stream>>>(x, aproj, ln1g, ln1b, x1f);
    // 5-6: gating
    gate1_kernel<<<Tt / 4, 256, 0, stream>>>(x1f, wg, idx1, idx2, gt1, gt2);
    gate2_kernel<<<1, 256, 0, stream>>>(idx1, idx2, gt1, gt2, p1, p2, k1, k2, w1c, w2c);
    // 7: dispatch
    hipMemsetAsync(ebuf, 0, (size_t)Ee * Cap * Dd * 2, stream);
    dispatch_kernel<<<Tt, 256, 0, stream>>>(x1f, idx1, p1, k1, idx2, p2, k2, ebuf);
    // 8-11: expert FFN — 256^2 dbuf counted-vmcnt GEMMs + bank swizzle
    tconv64_kernel<<<dim3(DFF / 64, Dd / 64, Ee), 256, 0, stream>>>(w1, wt, Dd, DFF);
    gemm_x2<1><<<dim3(DFF / 256, Cap / 256, Ee), 512, 0, stream>>>(
        ebuf, wt, hbuf, b1, Cap, DFF, Dd,
        (size_t)Cap * Dd, (size_t)DFF * Dd, (size_t)Cap * DFF, DFF);
    tconv64_kernel<<<dim3(Dd / 64, DFF / 64, Ee), 256, 0, stream>>>(w2, wt, DFF, Dd);
    gemm_x2<0><<<dim3(Dd / 256, Cap / 256, Ee), 512, 0, stream>>>(
        hbuf, wt, ybuf, b2, Cap, Dd, DFF,
        (size_t)Cap * DFF, (size_t)Dd * DFF, (size_t)Cap * Dd, Dd);
    // 12: combine + residual + LN2
    combine_ln2<<<Tt, 256, 0, stream>>>(x1f, ybuf, idx1, p1, w1c, idx2, p2, w2c, ln2g, ln2b, out);
}

// Round 13
// 1154.984 us; speedup vs baseline: 1.1095x; 1.0941x over previous
//
#include <hip/hip_runtime.h>
#include <cstdint>

#define DEVI __device__ __forceinline__

typedef short short8 __attribute__((ext_vector_type(8)));
typedef float f32x4 __attribute__((ext_vector_type(4)));
typedef unsigned short u16;
typedef u16 u16x4 __attribute__((ext_vector_type(4)));

static constexpr int Bz = 8, Ss = 1024, Dd = 1024, Hh = 16, HD = 64, DFF = 4096, Ee = 16;
static constexpr int Tt = Bz * Ss;           // 8192 tokens
static constexpr int Cap = (2 * Tt) / Ee;    // 1024 capacity
static constexpr int D3 = 3 * Dd;            // 3072
static constexpr float EPSc = 1.1920929e-07f;
static constexpr size_t PT = (size_t)Tt * Dd;   // plane elements (token-major)

DEVI u16 f2b(float f) {
    union { float f; uint32_t u; } v; v.f = f;
    return (u16)((v.u + 0x7FFFu + ((v.u >> 16) & 1u)) >> 16);
}
DEVI float b2f(u16 h) {
    union { uint32_t u; float f; } v; v.u = ((uint32_t)h) << 16; return v.f;
}
DEVI f32x4 zf4() { f32x4 v; v[0] = 0.f; v[1] = 0.f; v[2] = 0.f; v[3] = 0.f; return v; }

// async global->LDS, 16B per lane. LDS dest must be wave-uniform base + lane*16B.
DEVI void gl16(const u16* g, u16* l) {
    __builtin_amdgcn_global_load_lds(
        (const __attribute__((address_space(1))) void*)g,
        (__attribute__((address_space(3))) void*)l, 16, 0, 0);
}

// swizzled u16 index for [R][64] bf16 tiles (128B rows): byte ^= (row&7)<<4
DEVI int swzb(int row, int col) {
    int byte = (row * 64 + col) * 2;
    byte ^= (row & 7) << 4;
    return byte >> 1;
}

// ---------------------------------------------------------------------------
// split fp32 -> 3 bf16 planes (hi/mid/lo), plane stride = n. n % 1024 == 0.
// ---------------------------------------------------------------------------
__global__ __launch_bounds__(256)
void split3_kernel(const float* __restrict__ in, u16* __restrict__ out, long long n) {
    const long long i = ((long long)blockIdx.x * 256 + threadIdx.x) * 4;
    if (i >= n) return;
    const float4 v = *(const float4*)(in + i);
    const float f[4] = {v.x, v.y, v.z, v.w};
    u16x4 ph, pm, pl;
#pragma unroll
    for (int c = 0; c < 4; ++c) {
        const u16 hi = f2b(f[c]);
        const float r1 = f[c] - b2f(hi);     // exact
        const u16 mi = f2b(r1);
        const float r2 = r1 - b2f(mi);       // exact
        const u16 lo = f2b(r2);
        ph[c] = hi; pm[c] = mi; pl[c] = lo;
    }
    *(u16x4*)(out + i) = ph;
    *(u16x4*)(out + n + i) = pm;
    *(u16x4*)(out + 2 * n + i) = pl;
}

// ---------------------------------------------------------------------------
// transpose + convert, vectorized: in [Z][R][Cc] f32 -> out [Z][Cc][R] bf16
// ---------------------------------------------------------------------------
__global__ __launch_bounds__(256)
void tconv64_kernel(const float* __restrict__ in, u16* __restrict__ out, int R, int Cc) {
    __shared__ u16 tile[64][68];
    const int z = blockIdx.z;
    const int r0 = blockIdx.y * 64, c0 = blockIdx.x * 64;
    const int tr = threadIdx.x >> 4;          // 0..15
    const int tc4 = (threadIdx.x & 15) * 4;   // 0..60
    const float* ip = in + (size_t)z * R * Cc;
#pragma unroll
    for (int i = 0; i < 4; ++i) {
        const int row = tr + i * 16;
        const float4 v = *(const float4*)(ip + (size_t)(r0 + row) * Cc + c0 + tc4);
        u16x4 w;
        w[0] = f2b(v.x); w[1] = f2b(v.y); w[2] = f2b(v.z); w[3] = f2b(v.w);
        *(u16x4*)(&tile[row][tc4]) = w;
    }
    __syncthreads();
    u16* op = out + (size_t)z * R * Cc;
#pragma unroll
    for (int i = 0; i < 4; ++i) {
        const int orow = tr + i * 16;
        u16x4 w;
#pragma unroll
        for (int j = 0; j < 4; ++j) w[j] = tile[tc4 + j][orow];
        *(u16x4*)(op + (size_t)(c0 + orow) * R + r0 + tc4) = w;
    }
}

// ---------------------------------------------------------------------------
// V-plane transpose: vh/vl [Tt][Dd] (per bh: [s][64]) -> vth/vtl [bh][64][Ss]
// ---------------------------------------------------------------------------
__global__ __launch_bounds__(256)
void vtrans_kernel(const u16* __restrict__ vh, const u16* __restrict__ vl,
                   u16* __restrict__ vth, u16* __restrict__ vtl) {
    __shared__ u16 th[32][33], tl[32][33];
    const int bh = blockIdx.z, d0 = blockIdx.y * 32, s0 = blockIdx.x * 32;
    const int bb = bh >> 4, hh = bh & 15;
    const int tr = threadIdx.x >> 5, tc = threadIdx.x & 31;
#pragma unroll
    for (int i = 0; i < 4; ++i) {
        const size_t src = (size_t)(bb * Ss + s0 + tr + i * 8) * Dd + hh * HD + d0 + tc;
        th[tr + i * 8][tc] = vh[src];
        tl[tr + i * 8][tc] = vl[src];
    }
    __syncthreads();
#pragma unroll
    for (int i = 0; i < 4; ++i) {
        const size_t dst = ((size_t)bh * HD + d0 + tr + i * 8) * Ss + s0 + tc;
        vth[dst] = th[tc][tr + i * 8];
        vtl[dst] = tl[tc][tr + i * 8];
    }
}

// ---------------------------------------------------------------------------
// Split MFMA BT-GEMM (routing path) — proven 128x128 structure.
// SPLITS planes; FULLX=1 keeps all SPLITS^2 products (2-split full cross),
// FULLX=0 keeps triangular ap+bp<SPLITS (3-split, 6 products).
// MODE: 2 f32 out, 3 QKV split-plane out.
// ---------------------------------------------------------------------------
template <int SPLITS, int MODE, int FULLX = 0>
__global__ __launch_bounds__(256)
void gemm_gl(const u16* __restrict__ A, const u16* __restrict__ Bt, void* __restrict__ Cout,
             const float* __restrict__ bias, int M, int N, int K,
             size_t psA, size_t psB,
             u16* __restrict__ qh, u16* __restrict__ ql,
             u16* __restrict__ kh, u16* __restrict__ kl,
             u16* __restrict__ vh, u16* __restrict__ vl) {
    __shared__ u16 As[SPLITS * 128 * 32];
    __shared__ u16 Bs[SPLITS * 128 * 32];
    const int tid = threadIdx.x;
    const int lane = tid & 63, wid = tid >> 6;
    const int wm = wid >> 1, wn = wid & 1;
    const int m0 = blockIdx.y * 128, n0 = blockIdx.x * 128;
    const int lr = lane & 15, lg = lane >> 4;
    const int lrow = lane >> 2;          // 0..15
    const int lcol = (lane & 3) * 8;     // 0,8,16,24

    f32x4 acc[4][4];
#pragma unroll
    for (int i = 0; i < 4; ++i)
#pragma unroll
        for (int j = 0; j < 4; ++j) acc[i][j] = zf4();

    for (int kt = 0; kt < K; kt += 32) {
#pragma unroll
        for (int p = 0; p < SPLITS; ++p) {
#pragma unroll
            for (int c = 0; c < 2; ++c) {
                const int r0 = wid * 32 + c * 16;
                gl16(A + p * psA + (size_t)(m0 + r0 + lrow) * K + kt + lcol,
                     As + p * 4096 + r0 * 32 + lane * 8);
                gl16(Bt + p * psB + (size_t)(n0 + r0 + lrow) * K + kt + lcol,
                     Bs + p * 4096 + r0 * 32 + lane * 8);
            }
        }
        __syncthreads();

        short8 af[SPLITS][4];
#pragma unroll
        for (int p = 0; p < SPLITS; ++p)
#pragma unroll
            for (int i = 0; i < 4; ++i)
                af[p][i] = *(const short8*)(As + p * 4096 + (wm * 64 + i * 16 + lr) * 32 + lg * 8);

#pragma unroll
        for (int bp = 0; bp < SPLITS; ++bp) {
            short8 bf[4];
#pragma unroll
            for (int j = 0; j < 4; ++j)
                bf[j] = *(const short8*)(Bs + bp * 4096 + (wn * 64 + j * 16 + lr) * 32 + lg * 8);
#pragma unroll
            for (int ap = 0; ap < SPLITS; ++ap) {
                if (!FULLX && ap + bp >= SPLITS) continue;
#pragma unroll
                for (int i = 0; i < 4; ++i)
#pragma unroll
                    for (int j = 0; j < 4; ++j)
                        acc[i][j] = __builtin_amdgcn_mfma_f32_16x16x32_bf16(af[ap][i], bf[j], acc[i][j], 0, 0, 0);
            }
        }
        __syncthreads();
    }

    const int r4 = lg * 4;
    const int region = n0 >> 10;   // MODE 3: 0=Q,1=K,2=V (uniform per block)
#pragma unroll
    for (int j = 0; j < 4; ++j) {
        const int col = n0 + wn * 64 + j * 16 + lr;
        const float bv = bias[col];
#pragma unroll
        for (int i = 0; i < 4; ++i) {
#pragma unroll
            for (int r = 0; r < 4; ++r) {
                const int rowg = m0 + wm * 64 + i * 16 + r4 + r;
                float v = acc[i][j][r] + bv;
                if (MODE == 2) {
                    ((float*)Cout)[(size_t)rowg * N + col] = v;
                } else {
                    const size_t off = (size_t)rowg * Dd + (col & 1023);
                    if (region == 0) {
                        const float fs = v * 0.125f;
                        const u16 h = f2b(fs);
                        qh[off] = h; ql[off] = f2b(fs - b2f(h));
                    } else if (region == 1) {
                        const u16 h = f2b(v);
                        kh[off] = h; kl[off] = f2b(v - b2f(h));
                    } else {
                        const u16 h = f2b(v);
                        vh[off] = h; vl[off] = f2b(v - b2f(h));
                    }
                }
            }
        }
    }
}

// ---------------------------------------------------------------------------
// Expert GEMM, 256x256 tile, BK=64, 8 waves, double-buffered LDS,
// counted vmcnt(8) + XOR bank swizzle (validated rounds 7-12).
// ---------------------------------------------------------------------------
template <int RELU>
__global__ __launch_bounds__(512)
void gemm_x2(const u16* __restrict__ A, const u16* __restrict__ Bt, u16* __restrict__ Cout,
             const float* __restrict__ bias, int M, int N, int K,
             size_t sA, size_t sB, size_t sC, int sBias) {
    __shared__ u16 lds[2][2][256 * 64];   // 128 KiB
    const int tid = threadIdx.x, lane = tid & 63, wid = tid >> 6;
    const int wm = wid >> 2, wn = wid & 3;
    const int lr = lane & 15, lg = lane >> 4;
    const int m0 = blockIdx.y * 256, n0 = blockIdx.x * 256;
    const int e = blockIdx.z;
    const u16* Ab = A + (size_t)e * sA;
    const u16* Bb = Bt + (size_t)e * sB;

    const int srow = wid * 8 + (lane >> 3);
    const int sscol = (((lane & 7) ^ ((lane >> 3) & 7))) * 8;

    f32x4 acc[8][4];
#pragma unroll
    for (int i = 0; i < 8; ++i)
#pragma unroll
        for (int j = 0; j < 4; ++j) acc[i][j] = zf4();

#define STAGE_X2(b, kt)                                                              \
    {                                                                                \
        _Pragma("unroll")                                                            \
        for (int c = 0; c < 4; ++c)                                                  \
            gl16(Ab + (size_t)(m0 + c * 64 + srow) * K + (kt) + sscol,               \
                 &lds[b][0][(c * 64 + srow) * 64 + (lane & 7) * 8]);                 \
        _Pragma("unroll")                                                            \
        for (int c = 0; c < 4; ++c)                                                  \
            gl16(Bb + (size_t)(n0 + c * 64 + srow) * K + (kt) + sscol,               \
                 &lds[b][1][(c * 64 + srow) * 64 + (lane & 7) * 8]);                 \
    }

#define COMPUTE_X2(b)                                                                \
    {                                                                                \
        _Pragma("unroll")                                                            \
        for (int ks = 0; ks < 2; ++ks) {                                             \
            short8 af[8], bf[4];                                                     \
            _Pragma("unroll")                                                        \
            for (int i = 0; i < 8; ++i)                                              \
                af[i] = *(const short8*)(&lds[b][0][(wm * 128 + i * 16 + lr) * 64 +  \
                                                    (((ks * 4 + lg) ^ (lr & 7)) * 8)]); \
            _Pragma("unroll")                                                        \
            for (int j = 0; j < 4; ++j)                                              \
                bf[j] = *(const short8*)(&lds[b][1][(wn * 64 + j * 16 + lr) * 64 +   \
                                                    (((ks * 4 + lg) ^ (lr & 7)) * 8)]); \
            _Pragma("unroll")                                                        \
            for (int i = 0; i < 8; ++i)                                              \
                _Pragma("unroll")                                                    \
                for (int j = 0; j < 4; ++j)                                          \
                    acc[i][j] = __builtin_amdgcn_mfma_f32_16x16x32_bf16(af[i], bf[j], acc[i][j], 0, 0, 0); \
        }                                                                            \
    }

    const int nt = K >> 6;
    STAGE_X2(0, 0)
    for (int t = 0; t < nt - 1; ++t) {
        const int cur = t & 1;
        STAGE_X2(cur ^ 1, (t + 1) * 64)
        asm volatile("s_waitcnt vmcnt(8)" ::: "memory");
        __builtin_amdgcn_s_barrier();
        COMPUTE_X2(cur)
        asm volatile("s_waitcnt lgkmcnt(0)" ::: "memory");
        __builtin_amdgcn_s_barrier();
    }
    asm volatile("s_waitcnt vmcnt(0)" ::: "memory");
    __builtin_amdgcn_s_barrier();
    COMPUTE_X2((nt - 1) & 1)

#undef STAGE_X2
#undef COMPUTE_X2

    const int r4 = lg * 4;
#pragma unroll
    for (int j = 0; j < 4; ++j) {
        const int col = n0 + wn * 64 + j * 16 + lr;
        const float bv = bias[(size_t)e * sBias + col];
#pragma unroll
        for (int i = 0; i < 8; ++i) {
#pragma unroll
            for (int r = 0; r < 4; ++r) {
                const int rowg = m0 + wm * 128 + i * 16 + r4 + r;
                float v = acc[i][j][r] + bv;
                if (RELU) v = fmaxf(v, 0.f);
                Cout[(size_t)e * sC + (size_t)rowg * N + col] = f2b(v);
            }
        }
    }
}

// ---------------------------------------------------------------------------
// Split-bf16 MFMA flash attention (validated round-6/9/12 form, unchanged)
// ---------------------------------------------------------------------------
__global__ __launch_bounds__(256)
void attn_mfma(const u16* __restrict__ qhp, const u16* __restrict__ qlp,
               const u16* __restrict__ khp, const u16* __restrict__ klp,
               const u16* __restrict__ vthp, const u16* __restrict__ vtlp,
               u16* __restrict__ os) {
    __shared__ u16 Khi[64 * 64], Klo[64 * 64];
    __shared__ u16 Vhi[64 * 64], Vlo[64 * 64];   // [d][kk]
    __shared__ u16 Phi[4][16 * 64], Plo[4][16 * 64];

    const int qt = blockIdx.x, bh = blockIdx.y;
    const int bb = bh >> 4, hh = bh & 15;
    const int tid = threadIdx.x, lane = tid & 63, wid = tid >> 6;
    const int lr = lane & 15, lg = lane >> 4;

    short8 qhi[2], qlo[2];
    {
        const size_t qbase = (size_t)(bb * Ss + qt * 64 + wid * 16 + lr) * Dd + hh * HD;
#pragma unroll
        for (int ks = 0; ks < 2; ++ks) {
            qhi[ks] = *(const short8*)(qhp + qbase + ks * 32 + lg * 8);
            qlo[ks] = *(const short8*)(qlp + qbase + ks * 32 + lg * 8);
        }
    }

    float mrun[4], lrun[4];
    f32x4 oacc[4];
#pragma unroll
    for (int r = 0; r < 4; ++r) { mrun[r] = -1e30f; lrun[r] = 0.f; }
#pragma unroll
    for (int nf = 0; nf < 4; ++nf) oacc[nf] = zf4();

    const int srow = tid >> 2;        // 0..63
    const int sd = (tid & 3) * 16;    // 0,16,32,48

    u16* const PhiW = Phi[wid];
    u16* const PloW = Plo[wid];

    for (int kt = 0; kt < Ss / 64; ++kt) {
        const size_t krow = (size_t)(bb * Ss + kt * 64 + srow) * Dd + hh * HD + sd;
        const short8 k0 = *(const short8*)(khp + krow);
        const short8 k1 = *(const short8*)(khp + krow + 8);
        const short8 l0 = *(const short8*)(klp + krow);
        const short8 l1 = *(const short8*)(klp + krow + 8);
        const size_t vrow = ((size_t)bh * HD + srow) * Ss + kt * 64 + sd;
        const short8 v0 = *(const short8*)(vthp + vrow);
        const short8 v1 = *(const short8*)(vthp + vrow + 8);
        const short8 w0 = *(const short8*)(vtlp + vrow);
        const short8 w1 = *(const short8*)(vtlp + vrow + 8);
        __syncthreads();
        *(short8*)(Khi + swzb(srow, sd)) = k0;
        *(short8*)(Khi + swzb(srow, sd + 8)) = k1;
        *(short8*)(Klo + swzb(srow, sd)) = l0;
        *(short8*)(Klo + swzb(srow, sd + 8)) = l1;
        *(short8*)(Vhi + swzb(srow, sd)) = v0;
        *(short8*)(Vhi + swzb(srow, sd + 8)) = v1;
        *(short8*)(Vlo + swzb(srow, sd)) = w0;
        *(short8*)(Vlo + swzb(srow, sd + 8)) = w1;
        __syncthreads();

        f32x4 sc[4];
#pragma unroll
        for (int nf = 0; nf < 4; ++nf) sc[nf] = zf4();
#pragma unroll
        for (int nf = 0; nf < 4; ++nf)
#pragma unroll
            for (int ks = 0; ks < 2; ++ks) {
                const short8 kh = *(const short8*)(Khi + swzb(nf * 16 + lr, ks * 32 + lg * 8));
                const short8 kl = *(const short8*)(Klo + swzb(nf * 16 + lr, ks * 32 + lg * 8));
                sc[nf] = __builtin_amdgcn_mfma_f32_16x16x32_bf16(qhi[ks], kh, sc[nf], 0, 0, 0);
                sc[nf] = __builtin_amdgcn_mfma_f32_16x16x32_bf16(qhi[ks], kl, sc[nf], 0, 0, 0);
                sc[nf] = __builtin_amdgcn_mfma_f32_16x16x32_bf16(qlo[ks], kh, sc[nf], 0, 0, 0);
                sc[nf] = __builtin_amdgcn_mfma_f32_16x16x32_bf16(qlo[ks], kl, sc[nf], 0, 0, 0);
            }

        float scl[4];
#pragma unroll
        for (int r = 0; r < 4; ++r) {
            float m = fmaxf(fmaxf(sc[0][r], sc[1][r]), fmaxf(sc[2][r], sc[3][r]));
            m = fmaxf(m, __shfl_xor(m, 1));
            m = fmaxf(m, __shfl_xor(m, 2));
            m = fmaxf(m, __shfl_xor(m, 4));
            m = fmaxf(m, __shfl_xor(m, 8));
            const float mn = fmaxf(mrun[r], m);
            scl[r] = __expf(mrun[r] - mn);
            mrun[r] = mn;
            float s = 0.f;
#pragma unroll
            for (int nf = 0; nf < 4; ++nf) {
                const float p = __expf(sc[nf][r] - mn);
                sc[nf][r] = p;
                s += p;
            }
            s += __shfl_xor(s, 1);
            s += __shfl_xor(s, 2);
            s += __shfl_xor(s, 4);
            s += __shfl_xor(s, 8);
            lrun[r] = lrun[r] * scl[r] + s;
        }

#pragma unroll
        for (int nf = 0; nf < 4; ++nf)
#pragma unroll
            for (int r = 0; r < 4; ++r) {
                const float p = sc[nf][r];
                const u16 h = f2b(p);
                const int idx = swzb(lg * 4 + r, nf * 16 + lr);
                PhiW[idx] = h;
                PloW[idx] = f2b(p - b2f(h));
            }

#pragma unroll
        for (int nf = 0; nf < 4; ++nf)
#pragma unroll
            for (int r = 0; r < 4; ++r) oacc[nf][r] *= scl[r];

#pragma unroll
        for (int ks = 0; ks < 2; ++ks) {
            const short8 ph = *(const short8*)(PhiW + swzb(lr, ks * 32 + lg * 8));
            const short8 pl = *(const short8*)(PloW + swzb(lr, ks * 32 + lg * 8));
#pragma unroll
            for (int nf = 0; nf < 4; ++nf) {
                const short8 vh = *(const short8*)(Vhi + swzb(nf * 16 + lr, ks * 32 + lg * 8));
                const short8 vl = *(const short8*)(Vlo + swzb(nf * 16 + lr, ks * 32 + lg * 8));
                oacc[nf] = __builtin_amdgcn_mfma_f32_16x16x32_bf16(ph, vh, oacc[nf], 0, 0, 0);
                oacc[nf] = __builtin_amdgcn_mfma_f32_16x16x32_bf16(ph, vl, oacc[nf], 0, 0, 0);
                oacc[nf] = __builtin_amdgcn_mfma_f32_16x16x32_bf16(pl, vh, oacc[nf], 0, 0, 0);
                oacc[nf] = __builtin_amdgcn_mfma_f32_16x16x32_bf16(pl, vl, oacc[nf], 0, 0, 0);
            }
        }
    }

    // epilogue: 3-split planes (identical chain to split3_kernel)
#pragma unroll
    for (int r = 0; r < 4; ++r) {
        const float inv = 1.f / lrun[r];
        const size_t base = (size_t)(bb * Ss + qt * 64 + wid * 16 + lg * 4 + r) * Dd + hh * HD;
#pragma unroll
        for (int nf = 0; nf < 4; ++nf) {
            const float o = oacc[nf][r] * inv;
            const u16 h = f2b(o);
            const float r1 = o - b2f(h);
            const u16 m = f2b(r1);
            const u16 l = f2b(r1 - b2f(m));
            const size_t off = base + nf * 16 + lr;
            os[off] = h;
            os[PT + off] = m;
            os[2 * PT + off] = l;
        }
    }
}

// ---------------------------------------------------------------------------
DEVI double block_reduce_d(double v, double* sred, int tid) {
#pragma unroll
    for (int off = 32; off > 0; off >>= 1) v += __shfl_down(v, off);
    __syncthreads();
    if ((tid & 63) == 0) sred[tid >> 6] = v;
    __syncthreads();
    return sred[0] + sred[1] + sred[2] + sred[3];
}

// ---------------------------------------------------------------------------
// LN1: x1f = LN(x + aproj)
// ---------------------------------------------------------------------------
__global__ __launch_bounds__(256)
void ln1_kernel(const float* __restrict__ x, const float* __restrict__ ap,
                const float* __restrict__ g, const float* __restrict__ b,
                float* __restrict__ x1f) {
    __shared__ double sred[4];
    const int t = blockIdx.x, tid = threadIdx.x;
    const float4 xv = ((const float4*)(x + (size_t)t * Dd))[tid];
    const float4 av = ((const float4*)(ap + (size_t)t * Dd))[tid];
    const double v0 = (double)xv.x + (double)av.x;
    const double v1 = (double)xv.y + (double)av.y;
    const double v2 = (double)xv.z + (double)av.z;
    const double v3 = (double)xv.w + (double)av.w;
    const double s = block_reduce_d(v0 + v1 + v2 + v3, sred, tid);
    const double mean = s * (1.0 / Dd);
    const double c0 = v0 - mean, c1 = v1 - mean, c2 = v2 - mean, c3 = v3 - mean;
    const double s2 = block_reduce_d(c0 * c0 + c1 * c1 + c2 * c2 + c3 * c3, sred, tid);
    const double rstd = 1.0 / sqrt(s2 * (1.0 / Dd) + 1e-5);
    const float4 gv = ((const float4*)g)[tid];
    const float4 bv = ((const float4*)b)[tid];
    float4 ov;
    ov.x = (float)(c0 * rstd * (double)gv.x + (double)bv.x);
    ov.y = (float)(c1 * rstd * (double)gv.y + (double)bv.y);
    ov.z = (float)(c2 * rstd * (double)gv.z + (double)bv.z);
    ov.w = (float)(c3 * rstd * (double)gv.w + (double)bv.w);
    ((float4*)(x1f + (size_t)t * Dd))[tid] = ov;
}

// ---------------------------------------------------------------------------
// gating stage 1 (fp64)
// ---------------------------------------------------------------------------
__global__ __launch_bounds__(256)
void gate1_kernel(const float* __restrict__ x1f, const float* __restrict__ wg,
                  int* __restrict__ idx1, int* __restrict__ idx2,
                  float* __restrict__ gate1, float* __restrict__ gate2) {
    const int tid = threadIdx.x, lane = tid & 63, wid = tid >> 6;
    const int t = blockIdx.x * 4 + wid;
    double acc[16];
#pragma unroll
    for (int e = 0; e < 16; ++e) acc[e] = 0.0;
    for (int i = 0; i < 16; ++i) {
        const int d = i * 64 + lane;
        const double xv = (double)x1f[(size_t)t * Dd + d];
        const float4* wr = (const float4*)(wg + (size_t)d * 16);
        const float4 w0 = wr[0], w1 = wr[1], w2 = wr[2], w3 = wr[3];
        acc[0] += xv * (double)w0.x;  acc[1] += xv * (double)w0.y;
        acc[2] += xv * (double)w0.z;  acc[3] += xv * (double)w0.w;
        acc[4] += xv * (double)w1.x;  acc[5] += xv * (double)w1.y;
        acc[6] += xv * (double)w1.z;  acc[7] += xv * (double)w1.w;
        acc[8] += xv * (double)w2.x;  acc[9] += xv * (double)w2.y;
        acc[10] += xv * (double)w2.z; acc[11] += xv * (double)w2.w;
        acc[12] += xv * (double)w3.x; acc[13] += xv * (double)w3.y;
        acc[14] += xv * (double)w3.z; acc[15] += xv * (double)w3.w;
    }
#pragma unroll
    for (int e = 0; e < 16; ++e) {
        acc[e] += __shfl_xor(acc[e], 1);
        acc[e] += __shfl_xor(acc[e], 2);
        acc[e] += __shfl_xor(acc[e], 4);
        acc[e] += __shfl_xor(acc[e], 8);
        acc[e] += __shfl_xor(acc[e], 16);
        acc[e] += __shfl_xor(acc[e], 32);
    }
    if (lane == 0) {
        double mx = acc[0];
#pragma unroll
        for (int e = 1; e < 16; ++e) mx = fmax(mx, acc[e]);
        double z = 0.0, ex[16];
#pragma unroll
        for (int e = 0; e < 16; ++e) { ex[e] = exp(acc[e] - mx); z += ex[e]; }
        int b1 = 0; double v1 = acc[0];
#pragma unroll
        for (int e = 1; e < 16; ++e) if (acc[e] > v1) { v1 = acc[e]; b1 = e; }
        int b2 = (b1 == 0) ? 1 : 0; double v2 = acc[b2];
#pragma unroll
        for (int e = 0; e < 16; ++e) if (e != b1 && acc[e] > v2) { v2 = acc[e]; b2 = e; }
        const double rz = 1.0 / z;
        idx1[t] = b1; idx2[t] = b2;
        gate1[t] = (float)(ex[b1] * rz); gate2[t] = (float)(ex[b2] * rz);
    }
}

// ---------------------------------------------------------------------------
// gating stage 2 (single block; per-expert base update parallelized tid<16)
// ---------------------------------------------------------------------------
__global__ __launch_bounds__(256)
void gate2_kernel(const int* __restrict__ idx1, const int* __restrict__ idx2,
                  const float* __restrict__ gate1, const float* __restrict__ gate2,
                  int* __restrict__ p1, int* __restrict__ p2,
                  int* __restrict__ k1, int* __restrict__ k2,
                  float* __restrict__ w1, float* __restrict__ w2) {
    __shared__ int hist[16];
    __shared__ unsigned long long sb1[4][16], sb2[4][16];
    __shared__ int sbase1[16], sbase2[16];
    const int tid = threadIdx.x, lane = tid & 63, wid = tid >> 6;
    if (tid < 16) hist[tid] = 0;
    __syncthreads();
    for (int t = tid; t < Tt; t += 256) atomicAdd(&hist[idx1[t]], 1);
    __syncthreads();
    if (tid < 16) { sbase1[tid] = 0; sbase2[tid] = hist[tid]; }
    __syncthreads();
    const unsigned long long below = (1ULL << lane) - 1ULL;
    for (int ch = 0; ch < Tt / 256; ++ch) {
        const int t = ch * 256 + tid;
        const int a = idx1[t], b = idx2[t];
#pragma unroll
        for (int e = 0; e < 16; ++e) {
            const unsigned long long m1 = __ballot(a == e);
            const unsigned long long m2 = __ballot(b == e);
            if (lane == 0) { sb1[wid][e] = m1; sb2[wid][e] = m2; }
        }
        __syncthreads();
        int r1 = __popcll(sb1[wid][a] & below);
        int r2 = __popcll(sb2[wid][b] & below);
#pragma unroll
        for (int w = 0; w < 4; ++w)
            if (w < wid) { r1 += __popcll(sb1[w][a]); r2 += __popcll(sb2[w][b]); }
        const int loc1 = sbase1[a] + r1, loc2 = sbase2[b] + r2;
        const int kk1 = loc1 < Cap, kk2 = loc2 < Cap;
        const float g1 = kk1 ? gate1[t] : 0.f;
        const float g2 = kk2 ? gate2[t] : 0.f;
        const float dn = fmaxf(g1 + g2, EPSc);
        p1[t] = kk1 ? loc1 : 0;
        p2[t] = kk2 ? loc2 : 0;
        k1[t] = kk1; k2[t] = kk2;
        w1[t] = g1 / dn; w2[t] = g2 / dn;
        __syncthreads();
        if (tid < 16) {
            const int e = tid;
            int c1 = 0, c2 = 0;
#pragma unroll
            for (int w = 0; w < 4; ++w) { c1 += __popcll(sb1[w][e]); c2 += __popcll(sb2[w][e]); }
            sbase1[e] += c1; sbase2[e] += c2;
        }
        __syncthreads();
    }
}

// ---------------------------------------------------------------------------
// dispatch: scatter kept tokens (f32 -> bf16) into [E,C,D] buffers (pre-zeroed)
// ---------------------------------------------------------------------------
__global__ __launch_bounds__(256)
void dispatch_kernel(const float* __restrict__ x1f,
                     const int* __restrict__ i1, const int* __restrict__ p1, const int* __restrict__ k1,
                     const int* __restrict__ i2, const int* __restrict__ p2, const int* __restrict__ k2,
                     u16* __restrict__ buf) {
    const int t = blockIdx.x, tid = threadIdx.x;
    const float4 v = ((const float4*)(x1f + (size_t)t * Dd))[tid];
    u16x4 pw;
    pw[0] = f2b(v.x); pw[1] = f2b(v.y); pw[2] = f2b(v.z); pw[3] = f2b(v.w);
    if (k1[t]) *(u16x4*)(buf + ((size_t)i1[t] * Cap + p1[t]) * Dd + tid * 4) = pw;
    if (k2[t]) *(u16x4*)(buf + ((size_t)i2[t] * Cap + p2[t]) * Dd + tid * 4) = pw;
}

// ---------------------------------------------------------------------------
// combine + residual + LN2 -> d_out (f32)
// ---------------------------------------------------------------------------
__global__ __launch_bounds__(256)
void combine_ln2(const float* __restrict__ x1f, const u16* __restrict__ y,
                 const int* __restrict__ i1, const int* __restrict__ p1, const float* __restrict__ w1,
                 const int* __restrict__ i2, const int* __restrict__ p2, const float* __restrict__ w2,
                 const float* __restrict__ g, const float* __restrict__ b,
                 float* __restrict__ out) {
    __shared__ double sred[4];
    const int t = blockIdx.x, tid = threadIdx.x;
    const size_t r1 = ((size_t)i1[t] * Cap + p1[t]) * Dd;
    const size_t r2 = ((size_t)i2[t] * Cap + p2[t]) * Dd;
    const double a1 = (double)w1[t], a2 = (double)w2[t];
    const u16x4 y1 = *(const u16x4*)(y + r1 + tid * 4);
    const u16x4 y2 = *(const u16x4*)(y + r2 + tid * 4);
    const float4 xv = ((const float4*)(x1f + (size_t)t * Dd))[tid];
    const double v0 = (double)xv.x + a1 * (double)b2f(y1[0]) + a2 * (double)b2f(y2[0]);
    const double v1 = (double)xv.y + a1 * (double)b2f(y1[1]) + a2 * (double)b2f(y2[1]);
    const double v2 = (double)xv.z + a1 * (double)b2f(y1[2]) + a2 * (double)b2f(y2[2]);
    const double v3 = (double)xv.w + a1 * (double)b2f(y1[3]) + a2 * (double)b2f(y2[3]);
    const double s = block_reduce_d(v0 + v1 + v2 + v3, sred, tid);
    const double mean = s * (1.0 / Dd);
    const double c0 = v0 - mean, c1 = v1 - mean, c2 = v2 - mean, c3 = v3 - mean;
    const double s2 = block_reduce_d(c0 * c0 + c1 * c1 + c2 * c2 + c3 * c3, sred, tid);
    const double rstd = 1.0 / sqrt(s2 * (1.0 / Dd) + 1e-5);
    const float4 gv = ((const float4*)g)[tid];
    const float4 bv = ((const float4*)b)[tid];
    float4 ov;
    ov.x = (float)(c0 * rstd * (double)gv.x + (double)bv.x);
    ov.y = (float)(c1 * rstd * (double)gv.y + (double)bv.y);
    ov.z = (float)(c2 * rstd * (double)gv.z + (double)bv.z);
    ov.w = (float)(c3 * rstd * (double)gv.w + (double)bv.w);
    ((float4*)(out + (size_t)t * Dd))[tid] = ov;
}

// ---------------------------------------------------------------------------
extern "C" void kernel_launch(void* const* d_in, const int* in_sizes, int n_in,
                              void* d_out, int out_size, void* d_ws, size_t ws_size,
                              hipStream_t stream) {
    (void)in_sizes; (void)n_in; (void)out_size; (void)ws_size;
    const float* x    = (const float*)d_in[0];
    const float* inW  = (const float*)d_in[1];
    const float* inB  = (const float*)d_in[2];
    const float* outW = (const float*)d_in[3];
    const float* outB = (const float*)d_in[4];
    const float* ln1g = (const float*)d_in[5];
    const float* ln1b = (const float*)d_in[6];
    const float* ln2g = (const float*)d_in[7];
    const float* ln2b = (const float*)d_in[8];
    const float* wg   = (const float*)d_in[9];
    const float* w1   = (const float*)d_in[10];
    const float* b1   = (const float*)d_in[11];
    const float* w2   = (const float*)d_in[12];
    const float* b2   = (const float*)d_in[13];
    float* out = (float*)d_out;

    char* ws = (char*)d_ws;
    const size_t MB = 1024 * 1024;
    // ---- phase-overlapped arena (verified layout, peak 352.4 MiB) ----
    u16*   xs3   = (u16*)(ws + 0);          // [0,48)    dead after QKV gemm
    u16*   inW3  = (u16*)(ws + 48 * MB);    // [48,66)   dead after QKV gemm
    u16*   qh    = (u16*)(ws + 66 * MB);    // [66,82)   dead after attn
    u16*   ql    = (u16*)(ws + 82 * MB);    // [82,98)   dead after attn
    u16*   kh    = (u16*)(ws + 98 * MB);    // [98,114)  dead after attn
    u16*   kl    = (u16*)(ws + 114 * MB);   // [114,130) dead after attn
    u16*   vh    = (u16*)(ws + 130 * MB);   // [130,146) dead after vtrans
    u16*   vl    = (u16*)(ws + 146 * MB);   // [146,162) dead after vtrans
    u16*   vth   = (u16*)(ws + 162 * MB);   // [162,178) dead after attn
    u16*   vtl   = (u16*)(ws + 178 * MB);   // [178,194) dead after attn
    u16*   os3   = (u16*)(ws + 194 * MB);   // [194,242) attn out, dead after OP
    u16*   outW3 = (u16*)(ws + 0);          // [0,6)     over dead xs3, dead after OP
    float* aproj = (float*)(ws + 6 * MB);   // [6,38)    over dead xs3, dead after LN1
    u16*   wt    = (u16*)(ws + 0);          // [0,128)   written post-LN1 (all dead)
    u16*   hbuf  = (u16*)(ws + 128 * MB);   // [128,256) over dead kl-tail/v*/os3
    u16*   ybuf  = (u16*)(ws + 256 * MB);   // [256,288) fresh
    u16*   ebuf  = (u16*)(ws + 288 * MB);   // [288,320) fresh
    float* x1f   = (float*)(ws + 320 * MB); // [320,352) fresh, live till end
    char*  gbase = ws + 352 * MB;           // [352,~352.4) gating arrays
    int*   idx1 = (int*)(gbase + 0 * Tt * 4);
    int*   idx2 = (int*)(gbase + 1 * Tt * 4);
    float* gt1  = (float*)(gbase + 2 * Tt * 4);
    float* gt2  = (float*)(gbase + 3 * Tt * 4);
    int*   p1   = (int*)(gbase + 4 * Tt * 4);
    int*   p2   = (int*)(gbase + 5 * Tt * 4);
    int*   k1   = (int*)(gbase + 6 * Tt * 4);
    int*   k2   = (int*)(gbase + 7 * Tt * 4);
    float* w1c  = (float*)(gbase + 8 * Tt * 4);
    float* w2c  = (float*)(gbase + 9 * Tt * 4);

    const long long nTD = (long long)Tt * Dd;
    const long long nW1 = (long long)D3 * Dd;
    const long long nW2 = (long long)Dd * Dd;

    // 1: split inputs; QKV GEMM — 2-split full-cross (planes hi+mid)
    split3_kernel<<<(int)(nTD / 1024), 256, 0, stream>>>(x, xs3, nTD);
    split3_kernel<<<(int)(nW1 / 1024), 256, 0, stream>>>(inW, inW3, nW1);
    gemm_gl<2, 3, 1><<<dim3(D3 / 128, Tt / 128, 1), 256, 0, stream>>>(
        xs3, inW3, nullptr, inB, Tt, D3, Dd, (size_t)nTD, (size_t)nW1,
        qh, ql, kh, kl, vh, vl);
    // 2: V transpose; attention (validated kernel, unchanged)
    vtrans_kernel<<<dim3(Ss / 32, HD / 32, Bz * Hh), 256, 0, stream>>>(vh, vl, vth, vtl);
    attn_mfma<<<dim3(Ss / 64, Bz * Hh), 256, 0, stream>>>(qh, ql, kh, kl, vth, vtl, os3);
    // 3: out-proj — 2-split full-cross, f32 out
    split3_kernel<<<(int)(nW2 / 1024), 256, 0, stream>>>(outW, outW3, nW2);
    gemm_gl<2, 2, 1><<<dim3(Dd / 128, Tt / 128, 1), 256, 0, stream>>>(
        os3, outW3, aproj, outB, Tt, Dd, Dd, (size_t)nTD, (size_t)nW2,
        nullptr, nullptr, nullptr, nullptr, nullptr, nullptr);
    // 4: LN1
    ln1_kernel<<<Tt, 256, 0, stream>>>(x, aproj, ln1g, ln1b, x1f);
    // 5-6: gating
    gate1_kernel<<<Tt / 4, 256, 0, stream>>>(x1f, wg, idx1, idx2, gt1, gt2);
    gate2_kernel<<<1, 256, 0, stream>>>(idx1, idx2, gt1, gt2, p1, p2, k1, k2, w1c, w2c);
    // 7: dispatch
    hipMemsetAsync(ebuf, 0, (size_t)Ee * Cap * Dd * 2, stream);
    dispatch_kernel<<<Tt, 256, 0, stream>>>(x1f, idx1, p1, k1, idx2, p2, k2, ebuf);
    // 8-11: expert FFN — 256^2 dbuf counted-vmcnt GEMMs + bank swizzle
    tconv64_kernel<<<dim3(DFF / 64, Dd / 64, Ee), 256, 0, stream>>>(w1, wt, Dd, DFF);
    gemm_x2<1><<<dim3(DFF / 256, Cap / 256, Ee), 512, 0, stream>>>(
        ebuf, wt, hbuf, b1, Cap, DFF, Dd,
        (size_t)Cap * Dd, (size_t)DFF * Dd, (size_t)Cap * DFF, DFF);
    tconv64_kernel<<<dim3(Dd / 64, DFF / 64, Ee), 256, 0, stream>>>(w2, wt, DFF, Dd);
    gemm_x2<0><<<dim3(Dd / 256, Cap / 256, Ee), 512, 0, stream>>>(
        hbuf, wt, ybuf, b2, Cap, Dd, DFF,
        (size_t)Cap * DFF, (size_t)Dd * DFF, (size_t)Cap * Dd, Dd);
    // 12: combine + residual + LN2
    combine_ln2<<<Tt, 256, 0, stream>>>(x1f, ybuf, idx1, p1, w1c, idx2, p2, w2c, ln2g, ln2b, out);
}